// Round 7
// baseline (1602.756 us; speedup 1.0000x reference)
//
#include <hip/hip_runtime.h>

typedef unsigned short u16;
typedef unsigned int u32;
typedef unsigned long long u64;
typedef short short8_t __attribute__((ext_vector_type(8)));
typedef float f32x4 __attribute__((ext_vector_type(4)));
typedef float f32x2 __attribute__((ext_vector_type(2)));

#define SL 128
#define DM 256
#define RK 32
#define SEQ 512
#define NB 4
#define NCHUNK 4

__device__ __forceinline__ float bf2f(u16 u) {
  return __uint_as_float(((unsigned int)u) << 16);
}
__device__ __forceinline__ u16 f2bf(float f) {
  unsigned int x = __float_as_uint(f);
  x += 0x7fffu + ((x >> 16) & 1u);
  return (u16)(x >> 16);
}
// two bf16 packed in a u32 -> f32x2 {lo, hi}
__device__ __forceinline__ f32x2 bfpair(u32 u) {
  f32x2 r;
  r[0] = __uint_as_float(u << 16);
  r[1] = __uint_as_float(u & 0xffff0000u);
  return r;
}

// ----------------- f32 -> bf16 conversion (vectorized) ----------------------
__global__ __launch_bounds__(256) void cvt_k(const float* __restrict__ in,
                                             u16* __restrict__ out, int n4) {
  for (int i = blockIdx.x * blockDim.x + threadIdx.x; i < n4;
       i += gridDim.x * blockDim.x) {
    float4 v = ((const float4*)in)[i];
    unsigned int lo = (unsigned)f2bf(v.x) | ((unsigned)f2bf(v.y) << 16);
    unsigned int hi = (unsigned)f2bf(v.z) | ((unsigned)f2bf(v.w) << 16);
    ((uint2*)out)[i] = make_uint2(lo, hi);
  }
}

// ------- batched small cvt: 6 square weights (64K elems) + H (32K) ---------
struct CvtJobs { const float* src[7]; };
__global__ __launch_bounds__(256) void cvt_all_k(CvtJobs jobs,
    u16* __restrict__ wbase, u16* __restrict__ Hbf) {
  int z = blockIdx.y;
  const float* in = jobs.src[z];
  u16* out = (z < 6) ? (wbase + (size_t)z * 65536) : Hbf;
  int n4 = (z < 6) ? 16384 : 8192;
  for (int i = blockIdx.x * 256 + threadIdx.x; i < n4; i += gridDim.x * 256) {
    float4 v = ((const float4*)in)[i];
    unsigned int lo = (unsigned)f2bf(v.x) | ((unsigned)f2bf(v.y) << 16);
    unsigned int hi = (unsigned)f2bf(v.z) | ((unsigned)f2bf(v.w) << 16);
    ((uint2*)out)[i] = make_uint2(lo, hi);
  }
}

// ---------------- embedding: x = tok[id] + pos[s] (bf16 out) ----------------
__global__ __launch_bounds__(256) void embed_k(const int* __restrict__ ids,
    const float* __restrict__ tok, const float* __restrict__ pos,
    u16* __restrict__ xbf) {
  int bs = blockIdx.x, d = threadIdx.x;
  int id = ids[bs];
  int s = bs & (SEQ - 1);
  float v = tok[(size_t)id * DM + d] + pos[(size_t)s * DM + d];
  xbf[(size_t)bs * DM + d] = f2bf(v);
}

// ------------- generic NT GEMM: C[M,N] = A[M,256] * B[N,256]^T --------------
__global__ __launch_bounds__(256) void gemm_nt(const u16* __restrict__ A,
    const u16* __restrict__ Bw, float* __restrict__ Cout, int N) {
  __shared__ u16 s_a[64 * 256];
  __shared__ u16 s_b[64 * 256];
  int tid = threadIdx.x;
  int m0 = blockIdx.x * 64, n0 = blockIdx.y * 64;
  for (int c = tid; c < 2048; c += 256) {
    int row = c >> 5;
    int ec = (c & 31) << 3;
    short8_t va = *(const short8_t*)(A + (size_t)(m0 + row) * 256 + ec);
    short8_t vb = *(const short8_t*)(Bw + (size_t)(n0 + row) * 256 + ec);
    int sw = ec ^ ((row & 7) << 3);
    *(short8_t*)(&s_a[row * 256 + sw]) = va;
    *(short8_t*)(&s_b[row * 256 + sw]) = vb;
  }
  __syncthreads();
  int lane = tid & 63;
  int w = tid >> 6;
  int wm = (w >> 1) * 32, wn = (w & 1) * 32;
  int lr = lane & 15, lk = (lane >> 4) << 3;
  f32x4 acc00 = {0.f, 0.f, 0.f, 0.f};
  f32x4 acc01 = {0.f, 0.f, 0.f, 0.f};
  f32x4 acc10 = {0.f, 0.f, 0.f, 0.f};
  f32x4 acc11 = {0.f, 0.f, 0.f, 0.f};
#pragma unroll
  for (int ks = 0; ks < 8; ++ks) {
    int ke = ks * 32 + lk;
    int r0 = wm + lr, r1 = wm + 16 + lr;
    int c0 = wn + lr, c1 = wn + 16 + lr;
    short8_t a0 = *(const short8_t*)(&s_a[r0 * 256 + (ke ^ ((r0 & 7) << 3))]);
    short8_t a1 = *(const short8_t*)(&s_a[r1 * 256 + (ke ^ ((r1 & 7) << 3))]);
    short8_t b0 = *(const short8_t*)(&s_b[c0 * 256 + (ke ^ ((c0 & 7) << 3))]);
    short8_t b1 = *(const short8_t*)(&s_b[c1 * 256 + (ke ^ ((c1 & 7) << 3))]);
    acc00 = __builtin_amdgcn_mfma_f32_16x16x32_bf16(a0, b0, acc00, 0, 0, 0);
    acc01 = __builtin_amdgcn_mfma_f32_16x16x32_bf16(a0, b1, acc01, 0, 0, 0);
    acc10 = __builtin_amdgcn_mfma_f32_16x16x32_bf16(a1, b0, acc10, 0, 0, 0);
    acc11 = __builtin_amdgcn_mfma_f32_16x16x32_bf16(a1, b1, acc11, 0, 0, 0);
  }
  int rbase = (lane >> 4) << 2;
#pragma unroll
  for (int i = 0; i < 2; ++i) {
#pragma unroll
    for (int jj = 0; jj < 2; ++jj) {
      f32x4 v = (i == 0) ? (jj == 0 ? acc00 : acc01)
                         : (jj == 0 ? acc10 : acc11);
      int row0 = m0 + wm + i * 16 + rbase;
      int col = n0 + wn + jj * 16 + lr;
#pragma unroll
      for (int q = 0; q < 4; ++q)
        Cout[(size_t)(row0 + q) * (size_t)N + col] = v[q];
    }
  }
}

// ---- z-batched NT GEMM (N=256): B = wbase + qsel(z)*64K, C = Cb + z*cs -----
__global__ __launch_bounds__(256) void gemm_nt3(const u16* __restrict__ A,
    const u16* __restrict__ wbase, float* __restrict__ Cbase, int q0, int q1,
    int q2, size_t cstride) {
  int z = blockIdx.z;
  int q = (z == 0) ? q0 : ((z == 1) ? q1 : q2);
  const u16* Bw = wbase + (size_t)q * 65536;
  float* Cout = Cbase + (size_t)z * cstride;
  __shared__ u16 s_a[64 * 256];
  __shared__ u16 s_b[64 * 256];
  int tid = threadIdx.x;
  int m0 = blockIdx.x * 64, n0 = blockIdx.y * 64;
  for (int c = tid; c < 2048; c += 256) {
    int row = c >> 5;
    int ec = (c & 31) << 3;
    short8_t va = *(const short8_t*)(A + (size_t)(m0 + row) * 256 + ec);
    short8_t vb = *(const short8_t*)(Bw + (size_t)(n0 + row) * 256 + ec);
    int sw = ec ^ ((row & 7) << 3);
    *(short8_t*)(&s_a[row * 256 + sw]) = va;
    *(short8_t*)(&s_b[row * 256 + sw]) = vb;
  }
  __syncthreads();
  int lane = tid & 63;
  int w = tid >> 6;
  int wm = (w >> 1) * 32, wn = (w & 1) * 32;
  int lr = lane & 15, lk = (lane >> 4) << 3;
  f32x4 acc00 = {0.f, 0.f, 0.f, 0.f};
  f32x4 acc01 = {0.f, 0.f, 0.f, 0.f};
  f32x4 acc10 = {0.f, 0.f, 0.f, 0.f};
  f32x4 acc11 = {0.f, 0.f, 0.f, 0.f};
#pragma unroll
  for (int ks = 0; ks < 8; ++ks) {
    int ke = ks * 32 + lk;
    int r0 = wm + lr, r1 = wm + 16 + lr;
    int c0 = wn + lr, c1 = wn + 16 + lr;
    short8_t a0 = *(const short8_t*)(&s_a[r0 * 256 + (ke ^ ((r0 & 7) << 3))]);
    short8_t a1 = *(const short8_t*)(&s_a[r1 * 256 + (ke ^ ((r1 & 7) << 3))]);
    short8_t b0 = *(const short8_t*)(&s_b[c0 * 256 + (ke ^ ((c0 & 7) << 3))]);
    short8_t b1 = *(const short8_t*)(&s_b[c1 * 256 + (ke ^ ((c1 & 7) << 3))]);
    acc00 = __builtin_amdgcn_mfma_f32_16x16x32_bf16(a0, b0, acc00, 0, 0, 0);
    acc01 = __builtin_amdgcn_mfma_f32_16x16x32_bf16(a0, b1, acc01, 0, 0, 0);
    acc10 = __builtin_amdgcn_mfma_f32_16x16x32_bf16(a1, b0, acc10, 0, 0, 0);
    acc11 = __builtin_amdgcn_mfma_f32_16x16x32_bf16(a1, b1, acc11, 0, 0, 0);
  }
  int rbase = (lane >> 4) << 2;
#pragma unroll
  for (int i = 0; i < 2; ++i) {
#pragma unroll
    for (int jj = 0; jj < 2; ++jj) {
      f32x4 v = (i == 0) ? (jj == 0 ? acc00 : acc01)
                         : (jj == 0 ? acc10 : acc11);
      int row0 = m0 + wm + i * 16 + rbase;
      int col = n0 + wn + jj * 16 + lr;
#pragma unroll
      for (int q = 0; q < 4; ++q)
        Cout[(size_t)(row0 + q) * 256 + col] = v[q];
    }
  }
}

// ------ logits GEMM: 128x128 tile, K=256 in two 64KB LDS stages, NT C ------
__global__ __launch_bounds__(512) void gemm128(const u16* __restrict__ A,
    const u16* __restrict__ Bw, float* __restrict__ Cout, int N) {
  __shared__ u16 s_a[128 * 128];
  __shared__ u16 s_b[128 * 128];
  int tid = threadIdx.x;
  int n0 = blockIdx.x * 128, m0 = blockIdx.y * 128;
  int lane = tid & 63, w = tid >> 6;
  int wm = (w >> 1) * 32;
  int wn = (w & 1) * 64;
  int lr = lane & 15, lk = (lane >> 4) << 3;
  f32x4 acc[2][4];
#pragma unroll
  for (int i = 0; i < 2; ++i)
#pragma unroll
    for (int t = 0; t < 4; ++t) acc[i][t] = {0.f, 0.f, 0.f, 0.f};
#pragma unroll
  for (int kc = 0; kc < 2; ++kc) {
    if (kc) __syncthreads();
    for (int c = tid; c < 2048; c += 512) {
      int row = c >> 4;
      int ec = (c & 15) << 3;
      short8_t va =
          *(const short8_t*)(A + (size_t)(m0 + row) * 256 + kc * 128 + ec);
      short8_t vb =
          *(const short8_t*)(Bw + (size_t)(n0 + row) * 256 + kc * 128 + ec);
      int sw = ec ^ ((row & 7) << 3);
      *(short8_t*)(&s_a[row * 128 + sw]) = va;
      *(short8_t*)(&s_b[row * 128 + sw]) = vb;
    }
    __syncthreads();
#pragma unroll
    for (int ks = 0; ks < 4; ++ks) {
      int ke = ks * 32 + lk;
      int r0 = wm + lr, r1 = wm + 16 + lr;
      short8_t a0 =
          *(const short8_t*)(&s_a[r0 * 128 + (ke ^ ((r0 & 7) << 3))]);
      short8_t a1 =
          *(const short8_t*)(&s_a[r1 * 128 + (ke ^ ((r1 & 7) << 3))]);
#pragma unroll
      for (int t = 0; t < 4; ++t) {
        int c0 = wn + t * 16 + lr;
        short8_t b0 =
            *(const short8_t*)(&s_b[c0 * 128 + (ke ^ ((c0 & 7) << 3))]);
        acc[0][t] = __builtin_amdgcn_mfma_f32_16x16x32_bf16(a0, b0, acc[0][t], 0, 0, 0);
        acc[1][t] = __builtin_amdgcn_mfma_f32_16x16x32_bf16(a1, b0, acc[1][t], 0, 0, 0);
      }
    }
  }
  int rbase = (lane >> 4) << 2;
#pragma unroll
  for (int i = 0; i < 2; ++i) {
#pragma unroll
    for (int t = 0; t < 4; ++t) {
      int row0 = m0 + wm + i * 16 + rbase;
      int col = n0 + wn + t * 16 + lr;
#pragma unroll
      for (int q = 0; q < 4; ++q)
        __builtin_nontemporal_store(acc[i][t][q],
                                    &Cout[(size_t)(row0 + q) * (size_t)N + col]);
    }
  }
}

// ------- input compression attention: softmax over slots, then mask ---------
__global__ __launch_bounds__(128) void attn_in_k(const float* __restrict__ Qi,
    const float* __restrict__ Ksl, const int* __restrict__ am,
    float* __restrict__ Aout) {
  int bs = blockIdx.x, t = threadIdx.x;
  __shared__ float s_q[DM];
  __shared__ float sred[2];
  s_q[t] = Qi[(size_t)bs * DM + t];
  s_q[t + 128] = Qi[(size_t)bs * DM + t + 128];
  __syncthreads();
  const float* kr = Ksl + (size_t)t * DM;
  float sc = 0.f;
#pragma unroll 8
  for (int d = 0; d < DM; ++d) sc += s_q[d] * kr[d];
  sc *= 0.0625f;
  float mx = sc;
#pragma unroll
  for (int m = 1; m < 64; m <<= 1) mx = fmaxf(mx, __shfl_xor(mx, m));
  if ((t & 63) == 0) sred[t >> 6] = mx;
  __syncthreads();
  mx = fmaxf(sred[0], sred[1]);
  float p = expf(sc - mx);
  float sum = p;
#pragma unroll
  for (int m = 1; m < 64; m <<= 1) sum += __shfl_xor(sum, m);
  __syncthreads();
  if ((t & 63) == 0) sred[t >> 6] = sum;
  __syncthreads();
  sum = sred[0] + sred[1];
  p = (p / sum) * (float)am[bs];
  Aout[(size_t)bs * SL + t] = p;
}

// ---- partial column sums: dpart[sl][b*SL+k] = sum of 32 si; 16 slices ------
__global__ __launch_bounds__(512) void colsum_k(const float* __restrict__ A,
                                                float* __restrict__ dpart) {
  int t = threadIdx.x;
  int b = t >> 7, k = t & (SL - 1);
  int s0 = blockIdx.x * 32;
  const float* ap = A + (size_t)b * SEQ * SL + (size_t)s0 * SL + k;
  float s = 0.f;
#pragma unroll 4
  for (int si = 0; si < 32; ++si) s += ap[(size_t)si * SL];
  dpart[blockIdx.x * 512 + t] = s;
}

// ------ IR[b,k,d] = sum_s A[b,s,k]*Vi[b,s,d] / den;  Hs = H + IR ------------
__global__ __launch_bounds__(256) void irhs_k(const float* __restrict__ A,
    const float* __restrict__ Vi, const float* __restrict__ dpart,
    const float* __restrict__ H, float* __restrict__ Hs) {
  int k = blockIdx.x, b = blockIdx.y, d = threadIdx.x;
  float den = 1e-8f;
#pragma unroll
  for (int i = 0; i < 16; ++i) den += dpart[i * 512 + b * SL + k];
  const float* ap = A + (size_t)b * SEQ * SL + k;
  const float* vp = Vi + (size_t)b * SEQ * DM + d;
  float s = 0.f;
#pragma unroll 4
  for (int si = 0; si < SEQ; ++si)
    s += ap[(size_t)si * SL] * vp[(size_t)si * DM];
  Hs[((size_t)b * SL + k) * DM + d] = H[(size_t)k * DM + d] + s / den;
}

// -------------------- bilinear all-pairs slot mixing ------------------------
// 8 pairs per wave: block (j, ic) has 4 waves; wave wv owns i in
// [ic*32 + wv*8, +8). Software-pipelined: wt loads issued at iter top
// (outstanding through S), ws[next] ping-pong prefetched after S
// (outstanding through butterfly+T). sched_barrier(0) pins load blocks.
// Hs rows read from L2 (no LDS staging). NCHUNK=4 partials.
// MODE 0: bf16 W. MODE 1: f32 W + NT-write bf16 slabs. MODE 2: f32, no write.
template <int MODE>
__global__ __launch_bounds__(256, 2) void bilinear_k(
    const float* __restrict__ Hs, const void* __restrict__ Wsv,
    const void* __restrict__ Wtv, u16* __restrict__ Wsb,
    u16* __restrict__ Wtb, float* __restrict__ part) {
  int j = blockIdx.x, ic = blockIdx.y, tid = threadIdx.x;
  int wv = tid >> 6, ln = tid & 63;
  __shared__ float s_int[4][NB][RK];  // 2 KB, per-wave slot
  __shared__ float s_acc[4][NB][DM];  // 16 KB, per-wave slot
  int ibase = ic * 32 + wv * 8;

  if constexpr (MODE == 0) {
    const u16* Wsp = (const u16*)Wsv;
    const u16* Wtp = (const u16*)Wtv;
    f32x2 iacc[NB][4];
#pragma unroll
    for (int b = 0; b < NB; ++b)
#pragma unroll
      for (int q = 0; q < 4; ++q) iacc[b][q] = {0.f, 0.f};
    short8_t ws[2][16];
    {  // preamble: ws for pair 0
      size_t slab0 = (size_t)(ibase * SL + j) * (DM * RK);
#pragma unroll
      for (int t = 0; t < 16; ++t)
        ws[0][t] = __builtin_nontemporal_load(
            (const short8_t*)(Wsp + slab0 + t * 512 + ln * 8));
      __builtin_amdgcn_sched_barrier(0);
    }
#pragma unroll
    for (int p = 0; p < 8; ++p) {
      int cur = p & 1;
      int i = ibase + p;
      size_t slab = (size_t)(i * SL + j) * (DM * RK);
      short8_t wt[16];
#pragma unroll
      for (int t = 0; t < 16; ++t)
        wt[t] = __builtin_nontemporal_load(
            (const short8_t*)(Wtp + slab + t * 512 + ln * 8));
      __builtin_amdgcn_sched_barrier(0);
      // ---- S-phase: inter[b,r] = sum_d Hs[b,i,d]*Ws[d,r] ----
      f32x2 racc[NB][4];
#pragma unroll
      for (int b = 0; b < NB; ++b)
#pragma unroll
        for (int q = 0; q < 4; ++q) racc[b][q] = {0.f, 0.f};
#pragma unroll
      for (int t = 0; t < 16; ++t) {
        int d = t * 16 + (ln >> 2);
        uint4 wu = *(const uint4*)(&ws[cur][t]);
        f32x2 w0 = bfpair(wu.x), w1 = bfpair(wu.y);
        f32x2 w2 = bfpair(wu.z), w3 = bfpair(wu.w);
#pragma unroll
        for (int b = 0; b < NB; ++b) {
          float h = Hs[((size_t)b * SL + i) * DM + d];
          f32x2 h2 = {h, h};
          racc[b][0] += h2 * w0;
          racc[b][1] += h2 * w1;
          racc[b][2] += h2 * w2;
          racc[b][3] += h2 * w3;
        }
      }
      if (p < 7) {  // prefetch next pair's Ws (outstanding through bfly+T)
        size_t slabn = (size_t)((i + 1) * SL + j) * (DM * RK);
#pragma unroll
        for (int t = 0; t < 16; ++t)
          ws[cur ^ 1][t] = __builtin_nontemporal_load(
              (const short8_t*)(Wsp + slabn + t * 512 + ln * 8));
        __builtin_amdgcn_sched_barrier(0);
      }
      if (i != j) {
#pragma unroll
        for (int m = 4; m <= 32; m <<= 1)
#pragma unroll
          for (int b = 0; b < NB; ++b)
#pragma unroll
            for (int q = 0; q < 4; ++q) {
              f32x2 o;
              o[0] = __shfl_xor(racc[b][q][0], m);
              o[1] = __shfl_xor(racc[b][q][1], m);
              racc[b][q] += o;
            }
        if ((ln >> 2) == 0) {
          int r0 = (ln & 3) * 8;
#pragma unroll
          for (int b = 0; b < NB; ++b)
#pragma unroll
            for (int q = 0; q < 4; ++q) {
              s_int[wv][b][r0 + q * 2] = racc[b][q][0];
              s_int[wv][b][r0 + q * 2 + 1] = racc[b][q][1];
            }
        }
        // same-wave LDS write->read: in-order, no barrier needed
#pragma unroll
        for (int t = 0; t < 16; ++t) {
          int r = t * 2 + (ln >> 5);
          uint4 wu = *(const uint4*)(&wt[t]);
          f32x2 w0 = bfpair(wu.x), w1 = bfpair(wu.y);
          f32x2 w2 = bfpair(wu.z), w3 = bfpair(wu.w);
#pragma unroll
          for (int b = 0; b < NB; ++b) {
            float v = s_int[wv][b][r];
            f32x2 v2 = {v, v};
            iacc[b][0] += v2 * w0;
            iacc[b][1] += v2 * w1;
            iacc[b][2] += v2 * w2;
            iacc[b][3] += v2 * w3;
          }
        }
      }
    }
    // epilogue: combine lane-halves (r parity), write s_acc
#pragma unroll
    for (int b = 0; b < NB; ++b)
#pragma unroll
      for (int q = 0; q < 4; ++q) {
        f32x2 o;
        o[0] = __shfl_xor(iacc[b][q][0], 32);
        o[1] = __shfl_xor(iacc[b][q][1], 32);
        iacc[b][q] += o;
      }
    if (ln < 32) {
#pragma unroll
      for (int b = 0; b < NB; ++b)
#pragma unroll
        for (int q = 0; q < 4; ++q) {
          s_acc[wv][b][ln * 8 + q * 2] = iacc[b][q][0];
          s_acc[wv][b][ln * 8 + q * 2 + 1] = iacc[b][q][1];
        }
    }
  } else {
    const float* Wsp = (const float*)Wsv;
    const float* Wtp = (const float*)Wtv;
    float iacc[NB][4];
#pragma unroll
    for (int b = 0; b < NB; ++b)
#pragma unroll
      for (int q = 0; q < 4; ++q) iacc[b][q] = 0.f;
#pragma unroll 1
    for (int p = 0; p < 8; ++p) {
      int i = ibase + p;
      size_t slab = (size_t)(i * SL + j) * (DM * RK);
      const float* wp = Wsp + slab;
      const float* tp = Wtp + slab;
      f32x4 wsr[32];
#pragma unroll
      for (int t = 0; t < 32; ++t)
        wsr[t] =
            __builtin_nontemporal_load((const f32x4*)(wp + t * 256 + ln * 4));
      __builtin_amdgcn_sched_barrier(0);
      float racc[NB][4];
#pragma unroll
      for (int b = 0; b < NB; ++b)
#pragma unroll
        for (int q = 0; q < 4; ++q) racc[b][q] = 0.f;
#pragma unroll
      for (int t = 0; t < 32; ++t) {
        f32x4 w4 = wsr[t];
        int d = t * 8 + (ln >> 3);
#pragma unroll
        for (int b = 0; b < NB; ++b) {
          float h = Hs[((size_t)b * SL + i) * DM + d];
          racc[b][0] += h * w4[0];
          racc[b][1] += h * w4[1];
          racc[b][2] += h * w4[2];
          racc[b][3] += h * w4[3];
        }
        if constexpr (MODE == 1) {
          u64 pk = (u64)((unsigned)f2bf(w4[0]) | ((unsigned)f2bf(w4[1]) << 16)) |
                   ((u64)((unsigned)f2bf(w4[2]) | ((unsigned)f2bf(w4[3]) << 16))
                    << 32);
          __builtin_nontemporal_store(pk, (u64*)(Wsb + slab + t * 256 + ln * 4));
        }
      }
      if (i != j) {
#pragma unroll
        for (int m = 8; m <= 32; m <<= 1)
#pragma unroll
          for (int b = 0; b < NB; ++b)
#pragma unroll
            for (int q = 0; q < 4; ++q) racc[b][q] += __shfl_xor(racc[b][q], m);
        if ((ln >> 3) == 0) {
          int r0 = (ln & 7) * 4;
#pragma unroll
          for (int b = 0; b < NB; ++b)
#pragma unroll
            for (int q = 0; q < 4; ++q) s_int[wv][b][r0 + q] = racc[b][q];
        }
      }
#pragma unroll
      for (int c8 = 0; c8 < 4; ++c8) {
        f32x4 wtr[8];
#pragma unroll
        for (int t = 0; t < 8; ++t)
          wtr[t] = __builtin_nontemporal_load(
              (const f32x4*)(tp + (c8 * 8 + t) * 256 + ln * 4));
        __builtin_amdgcn_sched_barrier(0);
#pragma unroll
        for (int t = 0; t < 8; ++t) {
          int r = c8 * 8 + t;
          f32x4 w4 = wtr[t];
          if constexpr (MODE == 1) {
            u64 pk =
                (u64)((unsigned)f2bf(w4[0]) | ((unsigned)f2bf(w4[1]) << 16)) |
                ((u64)((unsigned)f2bf(w4[2]) | ((unsigned)f2bf(w4[3]) << 16))
                 << 32);
            __builtin_nontemporal_store(pk,
                                        (u64*)(Wtb + slab + r * 256 + ln * 4));
          }
          if (i != j) {
            float v0 = s_int[wv][0][r], v1 = s_int[wv][1][r];
            float v2 = s_int[wv][2][r], v3 = s_int[wv][3][r];
            iacc[0][0] += v0 * w4[0]; iacc[0][1] += v0 * w4[1];
            iacc[0][2] += v0 * w4[2]; iacc[0][3] += v0 * w4[3];
            iacc[1][0] += v1 * w4[0]; iacc[1][1] += v1 * w4[1];
            iacc[1][2] += v1 * w4[2]; iacc[1][3] += v1 * w4[3];
            iacc[2][0] += v2 * w4[0]; iacc[2][1] += v2 * w4[1];
            iacc[2][2] += v2 * w4[2]; iacc[2][3] += v2 * w4[3];
            iacc[3][0] += v3 * w4[0]; iacc[3][1] += v3 * w4[1];
            iacc[3][2] += v3 * w4[2]; iacc[3][3] += v3 * w4[3];
          }
        }
      }
    }
#pragma unroll
    for (int b = 0; b < NB; ++b)
#pragma unroll
      for (int q = 0; q < 4; ++q) s_acc[wv][b][ln * 4 + q] = iacc[b][q];
  }
  __syncthreads();
  for (int c = tid; c < NB * DM; c += 256) {
    int b = c >> 8, d = c & 255;
    float s = s_acc[0][b][d] + s_acc[1][b][d] + s_acc[2][b][d] + s_acc[3][b][d];
    part[(((size_t)ic * NB + b) * SL + j) * DM + d] = s;
  }
}

// ------- reduce partials + relu + residual + LayerNorm (per (b,j) row) ------
__global__ __launch_bounds__(256) void ln_k(float* __restrict__ Hs,
    const float* __restrict__ part, const float* __restrict__ g,
    const float* __restrict__ be, int last, u16* __restrict__ Hs_bf) {
  int j = blockIdx.x, b = blockIdx.y, d = threadIdx.x;
  size_t base = ((size_t)b * SL + j) * DM + d;
  float inf = 0.f;
#pragma unroll
  for (int icc = 0; icc < NCHUNK; ++icc)
    inf += part[(((size_t)icc * NB + b) * SL + j) * DM + d];
  float h = Hs[base] + fmaxf(inf, 0.f);
  float s1 = h, s2 = h * h;
#pragma unroll
  for (int m = 1; m < 64; m <<= 1) {
    s1 += __shfl_xor(s1, m);
    s2 += __shfl_xor(s2, m);
  }
  __shared__ float r1[4], r2[4];
  int wv = d >> 6;
  if ((d & 63) == 0) { r1[wv] = s1; r2[wv] = s2; }
  __syncthreads();
  s1 = r1[0] + r1[1] + r1[2] + r1[3];
  s2 = r2[0] + r2[1] + r2[2] + r2[3];
  float mu = s1 * (1.f / 256.f);
  float var = s2 * (1.f / 256.f) - mu * mu;
  float o = (h - mu) * rsqrtf(var + 1e-5f) * g[d] + be[d];
  Hs[base] = o;
  if (last) Hs_bf[base] = f2bf(o);
}

// ----------------- output expansion attention + Y (bf16) --------------------
__global__ __launch_bounds__(128) void attn_out_k(const float* __restrict__ Qo,
    const float* __restrict__ Kf, const float* __restrict__ Vf,
    u16* __restrict__ Ybf) {
  int bs = blockIdx.x, t = threadIdx.x;
  int b = bs >> 9;
  __shared__ float s_q[DM];
  __shared__ float s_p[SL];
  __shared__ float sred[2];
  s_q[t] = Qo[(size_t)bs * DM + t];
  s_q[t + 128] = Qo[(size_t)bs * DM + t + 128];
  __syncthreads();
  const float* kr = Kf + ((size_t)b * SL + t) * DM;
  float sc = 0.f;
#pragma unroll 8
  for (int d = 0; d < DM; ++d) sc += s_q[d] * kr[d];
  sc *= 0.0625f;
  float mx = sc;
#pragma unroll
  for (int m = 1; m < 64; m <<= 1) mx = fmaxf(mx, __shfl_xor(mx, m));
  if ((t & 63) == 0) sred[t >> 6] = mx;
  __syncthreads();
  mx = fmaxf(sred[0], sred[1]);
  float p = expf(sc - mx);
  float sum = p;
#pragma unroll
  for (int m = 1; m < 64; m <<= 1) sum += __shfl_xor(sum, m);
  __syncthreads();
  if ((t & 63) == 0) sred[t >> 6] = sum;
  __syncthreads();
  sum = sred[0] + sred[1];
  s_p[t] = p / sum;
  __syncthreads();
  for (int dd = t; dd < DM; dd += 128) {
    float y = 0.f;
    const float* vp = Vf + (size_t)b * SL * DM + dd;
#pragma unroll 8
    for (int k2 = 0; k2 < SL; ++k2) y += s_p[k2] * vp[(size_t)k2 * DM];
    Ybf[(size_t)bs * DM + dd] = f2bf(y);
  }
}

extern "C" void kernel_launch(void* const* d_in, const int* in_sizes, int n_in,
                              void* d_out, int out_size, void* d_ws,
                              size_t ws_size, hipStream_t stream) {
  (void)in_sizes; (void)n_in; (void)out_size;
  const int* ids = (const int*)d_in[0];
  const int* amask = (const int*)d_in[1];
  const float* tok = (const float*)d_in[2];
  const float* pos = (const float*)d_in[3];
  const float* Hsl = (const float*)d_in[4];
  const float* Ws = (const float*)d_in[5];
  const float* Wt = (const float*)d_in[6];
  const float* wq_in = (const float*)d_in[7];
  const float* wk_sl = (const float*)d_in[8];
  const float* wv_in = (const float*)d_in[9];
  const float* wq_out = (const float*)d_in[10];
  const float* wk_fin = (const float*)d_in[11];
  const float* wv_fin = (const float*)d_in[12];
  const float* w_out = (const float*)d_in[13];
  const float* lng = (const float*)d_in[14];
  const float* lnb = (const float*)d_in[15];

  char* base = (char*)d_ws;
  size_t used = 0;
  auto carve = [&](size_t bytes) {
    void* r = base + used;
    used += (bytes + 255) & ~(size_t)255;
    return r;
  };
  u16* x_bf = (u16*)carve((size_t)2048 * 256 * 2);
  float* Qi = (float*)carve((size_t)2048 * 256 * 4);
  float* Vi = (float*)carve((size_t)2048 * 256 * 4);
  float* Qo = (float*)carve((size_t)2048 * 256 * 4);
  float* Ksl = (float*)carve((size_t)128 * 256 * 4);
  float* Aat = (float*)carve((size_t)4 * 512 * 128 * 4);
  float* dpart = (float*)carve((size_t)16 * 512 * 4);
  float* Hst = (float*)carve((size_t)4 * 128 * 256 * 4);
  u16* Hs_bf = (u16*)carve((size_t)4 * 128 * 256 * 2);
  float* part = (float*)carve((size_t)NCHUNK * 4 * 128 * 256 * 4);
  float* Kf = (float*)carve((size_t)4 * 128 * 256 * 4);
  float* Vf = (float*)carve((size_t)4 * 128 * 256 * 4);
  u16* Ybf = (u16*)carve((size_t)2048 * 256 * 2);
  u16* wbase = (u16*)carve((size_t)6 * 65536 * 2);
  u16* Hbf = (u16*)carve((size_t)128 * 256 * 2);
  u16* w_out_bf = (u16*)carve((size_t)32000 * 256 * 2);
  const size_t WN = (size_t)128 * 128 * 256 * 32;
  bool bigws = (used + 2 * WN * 2 + 512) <= ws_size;
  u16* Ws_bf = nullptr;
  u16* Wt_bf = nullptr;
  if (bigws) {
    Ws_bf = (u16*)carve(WN * 2);
    Wt_bf = (u16*)carve(WN * 2);
  }

  CvtJobs cj;
  cj.src[0] = wq_in; cj.src[1] = wk_sl; cj.src[2] = wv_in;
  cj.src[3] = wq_out; cj.src[4] = wk_fin; cj.src[5] = wv_fin;
  cj.src[6] = Hsl;
  cvt_all_k<<<dim3(64, 7), 256, 0, stream>>>(cj, wbase, Hbf);
  cvt_k<<<2048, 256, 0, stream>>>(w_out, w_out_bf, (int)(32000 * 256 / 4));

  embed_k<<<2048, 256, 0, stream>>>(ids, tok, pos, x_bf);
  gemm_nt3<<<dim3(32, 4, 3), 256, 0, stream>>>(x_bf, wbase, Qi, 0, 2, 3,
                                               (size_t)2048 * 256);
  gemm_nt<<<dim3(2, 4), 256, 0, stream>>>(Hbf, wbase + (size_t)1 * 65536, Ksl,
                                          256);
  attn_in_k<<<2048, 128, 0, stream>>>(Qi, Ksl, amask, Aat);
  colsum_k<<<16, 512, 0, stream>>>(Aat, dpart);
  irhs_k<<<dim3(128, 4), 256, 0, stream>>>(Aat, Vi, dpart, Hsl, Hst);
  for (int step = 0; step < 6; ++step) {
    if (bigws) {
      if (step == 0)
        bilinear_k<1><<<dim3(SL, 4), 256, 0, stream>>>(Hst, Ws, Wt, Ws_bf,
                                                       Wt_bf, part);
      else
        bilinear_k<0><<<dim3(SL, 4), 256, 0, stream>>>(Hst, Ws_bf, Wt_bf,
                                                       nullptr, nullptr, part);
    } else {
      bilinear_k<2><<<dim3(SL, 4), 256, 0, stream>>>(Hst, Ws, Wt, nullptr,
                                                     nullptr, part);
    }
    ln_k<<<dim3(128, 4), 256, 0, stream>>>(Hst, part, lng + step * DM,
                                           lnb + step * DM, step == 5 ? 1 : 0,
                                           Hs_bf);
  }
  gemm_nt3<<<dim3(8, 4, 2), 256, 0, stream>>>(Hs_bf, wbase, Kf, 4, 5, 5,
                                              (size_t)4 * 128 * 256);
  attn_out_k<<<2048, 128, 0, stream>>>(Qo, Kf, Vf, Ybf);
  gemm128<<<dim3(250, 16), 512, 0, stream>>>(Ybf, w_out_bf, (float*)d_out,
                                             32000);
}

// Round 9
// 1029.494 us; speedup vs baseline: 1.5568x; 1.5568x over previous
//
#include <hip/hip_runtime.h>

typedef unsigned short u16;
typedef unsigned int u32;
typedef unsigned long long u64;
typedef short short8_t __attribute__((ext_vector_type(8)));
typedef float f32x4 __attribute__((ext_vector_type(4)));

#define SL 128
#define DM 256
#define RK 32
#define SEQ 512
#define NB 4
#define NCHUNK 8

__device__ __forceinline__ float bf2f(u16 u) {
  return __uint_as_float(((unsigned int)u) << 16);
}
__device__ __forceinline__ u16 f2bf(float f) {
  unsigned int x = __float_as_uint(f);
  x += 0x7fffu + ((x >> 16) & 1u);
  return (u16)(x >> 16);
}

// ----------------- f32 -> bf16 conversion (vectorized) ----------------------
__global__ __launch_bounds__(256) void cvt_k(const float* __restrict__ in,
                                             u16* __restrict__ out, int n4) {
  for (int i = blockIdx.x * blockDim.x + threadIdx.x; i < n4;
       i += gridDim.x * blockDim.x) {
    float4 v = ((const float4*)in)[i];
    unsigned int lo = (unsigned)f2bf(v.x) | ((unsigned)f2bf(v.y) << 16);
    unsigned int hi = (unsigned)f2bf(v.z) | ((unsigned)f2bf(v.w) << 16);
    ((uint2*)out)[i] = make_uint2(lo, hi);
  }
}

// ------- batched small cvt: 6 square weights (64K elems) + H (32K) ---------
struct CvtJobs { const float* src[7]; };
__global__ __launch_bounds__(256) void cvt_all_k(CvtJobs jobs,
    u16* __restrict__ wbase, u16* __restrict__ Hbf) {
  int z = blockIdx.y;
  const float* in = jobs.src[z];
  u16* out = (z < 6) ? (wbase + (size_t)z * 65536) : Hbf;
  int n4 = (z < 6) ? 16384 : 8192;
  for (int i = blockIdx.x * 256 + threadIdx.x; i < n4; i += gridDim.x * 256) {
    float4 v = ((const float4*)in)[i];
    unsigned int lo = (unsigned)f2bf(v.x) | ((unsigned)f2bf(v.y) << 16);
    unsigned int hi = (unsigned)f2bf(v.z) | ((unsigned)f2bf(v.w) << 16);
    ((uint2*)out)[i] = make_uint2(lo, hi);
  }
}

// ---------------- embedding: x = tok[id] + pos[s] (bf16 out) ----------------
__global__ __launch_bounds__(256) void embed_k(const int* __restrict__ ids,
    const float* __restrict__ tok, const float* __restrict__ pos,
    u16* __restrict__ xbf) {
  int bs = blockIdx.x, d = threadIdx.x;
  int id = ids[bs];
  int s = bs & (SEQ - 1);
  float v = tok[(size_t)id * DM + d] + pos[(size_t)s * DM + d];
  xbf[(size_t)bs * DM + d] = f2bf(v);
}

// ------------- generic NT GEMM: C[M,N] = A[M,256] * B[N,256]^T --------------
__global__ __launch_bounds__(256) void gemm_nt(const u16* __restrict__ A,
    const u16* __restrict__ Bw, float* __restrict__ Cout, int N) {
  __shared__ u16 s_a[64 * 256];
  __shared__ u16 s_b[64 * 256];
  int tid = threadIdx.x;
  int m0 = blockIdx.x * 64, n0 = blockIdx.y * 64;
  for (int c = tid; c < 2048; c += 256) {
    int row = c >> 5;
    int ec = (c & 31) << 3;
    short8_t va = *(const short8_t*)(A + (size_t)(m0 + row) * 256 + ec);
    short8_t vb = *(const short8_t*)(Bw + (size_t)(n0 + row) * 256 + ec);
    int sw = ec ^ ((row & 7) << 3);
    *(short8_t*)(&s_a[row * 256 + sw]) = va;
    *(short8_t*)(&s_b[row * 256 + sw]) = vb;
  }
  __syncthreads();
  int lane = tid & 63;
  int w = tid >> 6;
  int wm = (w >> 1) * 32, wn = (w & 1) * 32;
  int lr = lane & 15, lk = (lane >> 4) << 3;
  f32x4 acc00 = {0.f, 0.f, 0.f, 0.f};
  f32x4 acc01 = {0.f, 0.f, 0.f, 0.f};
  f32x4 acc10 = {0.f, 0.f, 0.f, 0.f};
  f32x4 acc11 = {0.f, 0.f, 0.f, 0.f};
#pragma unroll
  for (int ks = 0; ks < 8; ++ks) {
    int ke = ks * 32 + lk;
    int r0 = wm + lr, r1 = wm + 16 + lr;
    int c0 = wn + lr, c1 = wn + 16 + lr;
    short8_t a0 = *(const short8_t*)(&s_a[r0 * 256 + (ke ^ ((r0 & 7) << 3))]);
    short8_t a1 = *(const short8_t*)(&s_a[r1 * 256 + (ke ^ ((r1 & 7) << 3))]);
    short8_t b0 = *(const short8_t*)(&s_b[c0 * 256 + (ke ^ ((c0 & 7) << 3))]);
    short8_t b1 = *(const short8_t*)(&s_b[c1 * 256 + (ke ^ ((c1 & 7) << 3))]);
    acc00 = __builtin_amdgcn_mfma_f32_16x16x32_bf16(a0, b0, acc00, 0, 0, 0);
    acc01 = __builtin_amdgcn_mfma_f32_16x16x32_bf16(a0, b1, acc01, 0, 0, 0);
    acc10 = __builtin_amdgcn_mfma_f32_16x16x32_bf16(a1, b0, acc10, 0, 0, 0);
    acc11 = __builtin_amdgcn_mfma_f32_16x16x32_bf16(a1, b1, acc11, 0, 0, 0);
  }
  int rbase = (lane >> 4) << 2;
#pragma unroll
  for (int i = 0; i < 2; ++i) {
#pragma unroll
    for (int jj = 0; jj < 2; ++jj) {
      f32x4 v = (i == 0) ? (jj == 0 ? acc00 : acc01)
                         : (jj == 0 ? acc10 : acc11);
      int row0 = m0 + wm + i * 16 + rbase;
      int col = n0 + wn + jj * 16 + lr;
#pragma unroll
      for (int q = 0; q < 4; ++q)
        Cout[(size_t)(row0 + q) * (size_t)N + col] = v[q];
    }
  }
}

// ---- z-batched NT GEMM (N=256): B = wbase + qsel(z)*64K, C = Cb + z*cs -----
__global__ __launch_bounds__(256) void gemm_nt3(const u16* __restrict__ A,
    const u16* __restrict__ wbase, float* __restrict__ Cbase, int q0, int q1,
    int q2, size_t cstride) {
  int z = blockIdx.z;
  int q = (z == 0) ? q0 : ((z == 1) ? q1 : q2);
  const u16* Bw = wbase + (size_t)q * 65536;
  float* Cout = Cbase + (size_t)z * cstride;
  __shared__ u16 s_a[64 * 256];
  __shared__ u16 s_b[64 * 256];
  int tid = threadIdx.x;
  int m0 = blockIdx.x * 64, n0 = blockIdx.y * 64;
  for (int c = tid; c < 2048; c += 256) {
    int row = c >> 5;
    int ec = (c & 31) << 3;
    short8_t va = *(const short8_t*)(A + (size_t)(m0 + row) * 256 + ec);
    short8_t vb = *(const short8_t*)(Bw + (size_t)(n0 + row) * 256 + ec);
    int sw = ec ^ ((row & 7) << 3);
    *(short8_t*)(&s_a[row * 256 + sw]) = va;
    *(short8_t*)(&s_b[row * 256 + sw]) = vb;
  }
  __syncthreads();
  int lane = tid & 63;
  int w = tid >> 6;
  int wm = (w >> 1) * 32, wn = (w & 1) * 32;
  int lr = lane & 15, lk = (lane >> 4) << 3;
  f32x4 acc00 = {0.f, 0.f, 0.f, 0.f};
  f32x4 acc01 = {0.f, 0.f, 0.f, 0.f};
  f32x4 acc10 = {0.f, 0.f, 0.f, 0.f};
  f32x4 acc11 = {0.f, 0.f, 0.f, 0.f};
#pragma unroll
  for (int ks = 0; ks < 8; ++ks) {
    int ke = ks * 32 + lk;
    int r0 = wm + lr, r1 = wm + 16 + lr;
    int c0 = wn + lr, c1 = wn + 16 + lr;
    short8_t a0 = *(const short8_t*)(&s_a[r0 * 256 + (ke ^ ((r0 & 7) << 3))]);
    short8_t a1 = *(const short8_t*)(&s_a[r1 * 256 + (ke ^ ((r1 & 7) << 3))]);
    short8_t b0 = *(const short8_t*)(&s_b[c0 * 256 + (ke ^ ((c0 & 7) << 3))]);
    short8_t b1 = *(const short8_t*)(&s_b[c1 * 256 + (ke ^ ((c1 & 7) << 3))]);
    acc00 = __builtin_amdgcn_mfma_f32_16x16x32_bf16(a0, b0, acc00, 0, 0, 0);
    acc01 = __builtin_amdgcn_mfma_f32_16x16x32_bf16(a0, b1, acc01, 0, 0, 0);
    acc10 = __builtin_amdgcn_mfma_f32_16x16x32_bf16(a1, b0, acc10, 0, 0, 0);
    acc11 = __builtin_amdgcn_mfma_f32_16x16x32_bf16(a1, b1, acc11, 0, 0, 0);
  }
  int rbase = (lane >> 4) << 2;
#pragma unroll
  for (int i = 0; i < 2; ++i) {
#pragma unroll
    for (int jj = 0; jj < 2; ++jj) {
      f32x4 v = (i == 0) ? (jj == 0 ? acc00 : acc01)
                         : (jj == 0 ? acc10 : acc11);
      int row0 = m0 + wm + i * 16 + rbase;
      int col = n0 + wn + jj * 16 + lr;
#pragma unroll
      for (int q = 0; q < 4; ++q)
        Cout[(size_t)(row0 + q) * 256 + col] = v[q];
    }
  }
}

// ------ logits GEMM: 128x128 tile, K=256 in two 64KB LDS stages, NT C ------
__global__ __launch_bounds__(512) void gemm128(const u16* __restrict__ A,
    const u16* __restrict__ Bw, float* __restrict__ Cout, int N) {
  __shared__ u16 s_a[128 * 128];
  __shared__ u16 s_b[128 * 128];
  int tid = threadIdx.x;
  int n0 = blockIdx.x * 128, m0 = blockIdx.y * 128;
  int lane = tid & 63, w = tid >> 6;
  int wm = (w >> 1) * 32;
  int wn = (w & 1) * 64;
  int lr = lane & 15, lk = (lane >> 4) << 3;
  f32x4 acc[2][4];
#pragma unroll
  for (int i = 0; i < 2; ++i)
#pragma unroll
    for (int t = 0; t < 4; ++t) acc[i][t] = {0.f, 0.f, 0.f, 0.f};
#pragma unroll
  for (int kc = 0; kc < 2; ++kc) {
    if (kc) __syncthreads();
    for (int c = tid; c < 2048; c += 512) {
      int row = c >> 4;
      int ec = (c & 15) << 3;
      short8_t va =
          *(const short8_t*)(A + (size_t)(m0 + row) * 256 + kc * 128 + ec);
      short8_t vb =
          *(const short8_t*)(Bw + (size_t)(n0 + row) * 256 + kc * 128 + ec);
      int sw = ec ^ ((row & 7) << 3);
      *(short8_t*)(&s_a[row * 128 + sw]) = va;
      *(short8_t*)(&s_b[row * 128 + sw]) = vb;
    }
    __syncthreads();
#pragma unroll
    for (int ks = 0; ks < 4; ++ks) {
      int ke = ks * 32 + lk;
      int r0 = wm + lr, r1 = wm + 16 + lr;
      short8_t a0 =
          *(const short8_t*)(&s_a[r0 * 128 + (ke ^ ((r0 & 7) << 3))]);
      short8_t a1 =
          *(const short8_t*)(&s_a[r1 * 128 + (ke ^ ((r1 & 7) << 3))]);
#pragma unroll
      for (int t = 0; t < 4; ++t) {
        int c0 = wn + t * 16 + lr;
        short8_t b0 =
            *(const short8_t*)(&s_b[c0 * 128 + (ke ^ ((c0 & 7) << 3))]);
        acc[0][t] = __builtin_amdgcn_mfma_f32_16x16x32_bf16(a0, b0, acc[0][t], 0, 0, 0);
        acc[1][t] = __builtin_amdgcn_mfma_f32_16x16x32_bf16(a1, b0, acc[1][t], 0, 0, 0);
      }
    }
  }
  int rbase = (lane >> 4) << 2;
#pragma unroll
  for (int i = 0; i < 2; ++i) {
#pragma unroll
    for (int t = 0; t < 4; ++t) {
      int row0 = m0 + wm + i * 16 + rbase;
      int col = n0 + wn + t * 16 + lr;
#pragma unroll
      for (int q = 0; q < 4; ++q)
        __builtin_nontemporal_store(acc[i][t][q],
                                    &Cout[(size_t)(row0 + q) * (size_t)N + col]);
    }
  }
}

// ------- input compression attention: softmax over slots, then mask ---------
__global__ __launch_bounds__(128) void attn_in_k(const float* __restrict__ Qi,
    const float* __restrict__ Ksl, const int* __restrict__ am,
    float* __restrict__ Aout) {
  int bs = blockIdx.x, t = threadIdx.x;
  __shared__ float s_q[DM];
  __shared__ float sred[2];
  s_q[t] = Qi[(size_t)bs * DM + t];
  s_q[t + 128] = Qi[(size_t)bs * DM + t + 128];
  __syncthreads();
  const float* kr = Ksl + (size_t)t * DM;
  float sc = 0.f;
#pragma unroll 8
  for (int d = 0; d < DM; ++d) sc += s_q[d] * kr[d];
  sc *= 0.0625f;
  float mx = sc;
#pragma unroll
  for (int m = 1; m < 64; m <<= 1) mx = fmaxf(mx, __shfl_xor(mx, m));
  if ((t & 63) == 0) sred[t >> 6] = mx;
  __syncthreads();
  mx = fmaxf(sred[0], sred[1]);
  float p = expf(sc - mx);
  float sum = p;
#pragma unroll
  for (int m = 1; m < 64; m <<= 1) sum += __shfl_xor(sum, m);
  __syncthreads();
  if ((t & 63) == 0) sred[t >> 6] = sum;
  __syncthreads();
  sum = sred[0] + sred[1];
  p = (p / sum) * (float)am[bs];
  Aout[(size_t)bs * SL + t] = p;
}

// ---- partial column sums: dpart[sl][b*SL+k] = sum of 32 si; 16 slices ------
__global__ __launch_bounds__(512) void colsum_k(const float* __restrict__ A,
                                                float* __restrict__ dpart) {
  int t = threadIdx.x;
  int b = t >> 7, k = t & (SL - 1);
  int s0 = blockIdx.x * 32;
  const float* ap = A + (size_t)b * SEQ * SL + (size_t)s0 * SL + k;
  float s = 0.f;
#pragma unroll 4
  for (int si = 0; si < 32; ++si) s += ap[(size_t)si * SL];
  dpart[blockIdx.x * 512 + t] = s;
}

// ------ IR[b,k,d] = sum_s A[b,s,k]*Vi[b,s,d] / den;  Hs = H + IR ------------
__global__ __launch_bounds__(256) void irhs_k(const float* __restrict__ A,
    const float* __restrict__ Vi, const float* __restrict__ dpart,
    const float* __restrict__ H, float* __restrict__ Hs) {
  int k = blockIdx.x, b = blockIdx.y, d = threadIdx.x;
  float den = 1e-8f;
#pragma unroll
  for (int i = 0; i < 16; ++i) den += dpart[i * 512 + b * SL + k];
  const float* ap = A + (size_t)b * SEQ * SL + k;
  const float* vp = Vi + (size_t)b * SEQ * DM + d;
  float s = 0.f;
#pragma unroll 4
  for (int si = 0; si < SEQ; ++si)
    s += ap[(size_t)si * SL] * vp[(size_t)si * DM];
  Hs[((size_t)b * SL + k) * DM + d] = H[(size_t)k * DM + d] + s / den;
}

// -------------------- bilinear all-pairs slot mixing ------------------------
// 4 pairs per wave: block (j, ic) has 4 waves; wave wv owns i in
// [ic*16 + wv*4, +4). Grid (128, 8) = 1024 blocks -> 4 blocks/CU (16
// waves/CU) so HBM latency is hidden by TLP, not per-wave pipelining.
// MODE 0: bf16 W (R6-proven flat body, 68 VGPR). MODE 1: f32 W chunked
// 8xf32x4 bursts (no 128-reg array -> no spill) + NT-write bf16 slabs.
// MODE 2: f32, no write.
template <int MODE>
__global__ __launch_bounds__(256) void bilinear_k(
    const float* __restrict__ Hs, const void* __restrict__ Wsv,
    const void* __restrict__ Wtv, u16* __restrict__ Wsb,
    u16* __restrict__ Wtb, float* __restrict__ part) {
  int j = blockIdx.x, ic = blockIdx.y, tid = threadIdx.x;
  int wv = tid >> 6, ln = tid & 63;
  __shared__ float s_int[4][NB][RK];  // 2 KB, per-wave slot
  __shared__ float s_acc[4][NB][DM];  // 16 KB, per-wave slot
  int ibase = ic * 16 + wv * 4;

  if constexpr (MODE == 0) {
    const u16* Wsp = (const u16*)Wsv;
    const u16* Wtp = (const u16*)Wtv;
    float iacc[NB][8];
#pragma unroll
    for (int b = 0; b < NB; ++b)
#pragma unroll
      for (int q = 0; q < 8; ++q) iacc[b][q] = 0.f;
#pragma unroll 1
    for (int p = 0; p < 4; ++p) {
      int i = ibase + p;
      if (i == j) continue;
      size_t slab = (size_t)(i * SL + j) * (DM * RK);
      const u16* wp = Wsp + slab;
      const u16* tp = Wtp + slab;
      short8_t wsr[16], wtr[16];
#pragma unroll
      for (int t = 0; t < 16; ++t)
        wsr[t] = __builtin_nontemporal_load(
            (const short8_t*)(wp + t * 512 + ln * 8));
#pragma unroll
      for (int t = 0; t < 16; ++t)
        wtr[t] = __builtin_nontemporal_load(
            (const short8_t*)(tp + t * 512 + ln * 8));
      float racc[NB][8];
#pragma unroll
      for (int b = 0; b < NB; ++b)
#pragma unroll
        for (int q = 0; q < 8; ++q) racc[b][q] = 0.f;
#pragma unroll
      for (int t = 0; t < 16; ++t) {
        int d = t * 16 + (ln >> 2);
        float h0 = Hs[((size_t)0 * SL + i) * DM + d];
        float h1 = Hs[((size_t)1 * SL + i) * DM + d];
        float h2 = Hs[((size_t)2 * SL + i) * DM + d];
        float h3 = Hs[((size_t)3 * SL + i) * DM + d];
#pragma unroll
        for (int q = 0; q < 8; ++q) {
          float wf = bf2f((u16)wsr[t][q]);
          racc[0][q] += h0 * wf;
          racc[1][q] += h1 * wf;
          racc[2][q] += h2 * wf;
          racc[3][q] += h3 * wf;
        }
      }
#pragma unroll
      for (int m = 4; m <= 32; m <<= 1)
#pragma unroll
        for (int b = 0; b < NB; ++b)
#pragma unroll
          for (int q = 0; q < 8; ++q) racc[b][q] += __shfl_xor(racc[b][q], m);
      if ((ln >> 2) == 0) {
        int r0 = (ln & 3) * 8;
#pragma unroll
        for (int b = 0; b < NB; ++b)
#pragma unroll
          for (int q = 0; q < 8; ++q) s_int[wv][b][r0 + q] = racc[b][q];
      }
      // same-wave LDS write->read: in-order, no barrier needed
#pragma unroll
      for (int t = 0; t < 16; ++t) {
        int r = t * 2 + (ln >> 5);
        float v0 = s_int[wv][0][r], v1 = s_int[wv][1][r];
        float v2 = s_int[wv][2][r], v3 = s_int[wv][3][r];
#pragma unroll
        for (int q = 0; q < 8; ++q) {
          float wf = bf2f((u16)wtr[t][q]);
          iacc[0][q] += v0 * wf;
          iacc[1][q] += v1 * wf;
          iacc[2][q] += v2 * wf;
          iacc[3][q] += v3 * wf;
        }
      }
    }
#pragma unroll
    for (int b = 0; b < NB; ++b)
#pragma unroll
      for (int q = 0; q < 8; ++q) iacc[b][q] += __shfl_xor(iacc[b][q], 32);
    if (ln < 32) {
#pragma unroll
      for (int b = 0; b < NB; ++b)
#pragma unroll
        for (int q = 0; q < 8; ++q) s_acc[wv][b][ln * 8 + q] = iacc[b][q];
    }
  } else {
    const float* Wsp = (const float*)Wsv;
    const float* Wtp = (const float*)Wtv;
    float iacc[NB][4];
#pragma unroll
    for (int b = 0; b < NB; ++b)
#pragma unroll
      for (int q = 0; q < 4; ++q) iacc[b][q] = 0.f;
#pragma unroll 1
    for (int p = 0; p < 4; ++p) {
      int i = ibase + p;
      size_t slab = (size_t)(i * SL + j) * (DM * RK);
      const float* wp = Wsp + slab;
      const float* tp = Wtp + slab;
      float racc[NB][4];
#pragma unroll
      for (int b = 0; b < NB; ++b)
#pragma unroll
        for (int q = 0; q < 4; ++q) racc[b][q] = 0.f;
      // S-phase in 4 chunks of 8 f32x4 (keeps ~32 data regs live)
#pragma unroll
      for (int c8 = 0; c8 < 4; ++c8) {
        f32x4 wsr[8];
#pragma unroll
        for (int t = 0; t < 8; ++t)
          wsr[t] = __builtin_nontemporal_load(
              (const f32x4*)(wp + (c8 * 8 + t) * 256 + ln * 4));
#pragma unroll
        for (int t = 0; t < 8; ++t) {
          int tt = c8 * 8 + t;
          f32x4 w4 = wsr[t];
          int d = tt * 8 + (ln >> 3);
#pragma unroll
          for (int b = 0; b < NB; ++b) {
            float h = Hs[((size_t)b * SL + i) * DM + d];
            racc[b][0] += h * w4[0];
            racc[b][1] += h * w4[1];
            racc[b][2] += h * w4[2];
            racc[b][3] += h * w4[3];
          }
          if constexpr (MODE == 1) {
            u64 pk =
                (u64)((unsigned)f2bf(w4[0]) | ((unsigned)f2bf(w4[1]) << 16)) |
                ((u64)((unsigned)f2bf(w4[2]) | ((unsigned)f2bf(w4[3]) << 16))
                 << 32);
            __builtin_nontemporal_store(pk,
                                        (u64*)(Wsb + slab + tt * 256 + ln * 4));
          }
        }
      }
      if (i != j) {
#pragma unroll
        for (int m = 8; m <= 32; m <<= 1)
#pragma unroll
          for (int b = 0; b < NB; ++b)
#pragma unroll
            for (int q = 0; q < 4; ++q) racc[b][q] += __shfl_xor(racc[b][q], m);
        if ((ln >> 3) == 0) {
          int r0 = (ln & 7) * 4;
#pragma unroll
          for (int b = 0; b < NB; ++b)
#pragma unroll
            for (int q = 0; q < 4; ++q) s_int[wv][b][r0 + q] = racc[b][q];
        }
      }
#pragma unroll
      for (int c8 = 0; c8 < 4; ++c8) {
        f32x4 wtr[8];
#pragma unroll
        for (int t = 0; t < 8; ++t)
          wtr[t] = __builtin_nontemporal_load(
              (const f32x4*)(tp + (c8 * 8 + t) * 256 + ln * 4));
#pragma unroll
        for (int t = 0; t < 8; ++t) {
          int r = c8 * 8 + t;
          f32x4 w4 = wtr[t];
          if constexpr (MODE == 1) {
            u64 pk =
                (u64)((unsigned)f2bf(w4[0]) | ((unsigned)f2bf(w4[1]) << 16)) |
                ((u64)((unsigned)f2bf(w4[2]) | ((unsigned)f2bf(w4[3]) << 16))
                 << 32);
            __builtin_nontemporal_store(pk,
                                        (u64*)(Wtb + slab + r * 256 + ln * 4));
          }
          if (i != j) {
            float v0 = s_int[wv][0][r], v1 = s_int[wv][1][r];
            float v2 = s_int[wv][2][r], v3 = s_int[wv][3][r];
            iacc[0][0] += v0 * w4[0]; iacc[0][1] += v0 * w4[1];
            iacc[0][2] += v0 * w4[2]; iacc[0][3] += v0 * w4[3];
            iacc[1][0] += v1 * w4[0]; iacc[1][1] += v1 * w4[1];
            iacc[1][2] += v1 * w4[2]; iacc[1][3] += v1 * w4[3];
            iacc[2][0] += v2 * w4[0]; iacc[2][1] += v2 * w4[1];
            iacc[2][2] += v2 * w4[2]; iacc[2][3] += v2 * w4[3];
            iacc[3][0] += v3 * w4[0]; iacc[3][1] += v3 * w4[1];
            iacc[3][2] += v3 * w4[2]; iacc[3][3] += v3 * w4[3];
          }
        }
      }
    }
#pragma unroll
    for (int b = 0; b < NB; ++b)
#pragma unroll
      for (int q = 0; q < 4; ++q) s_acc[wv][b][ln * 4 + q] = iacc[b][q];
  }
  __syncthreads();
  for (int c = tid; c < NB * DM; c += 256) {
    int b = c >> 8, d = c & 255;
    float s = s_acc[0][b][d] + s_acc[1][b][d] + s_acc[2][b][d] + s_acc[3][b][d];
    part[(((size_t)ic * NB + b) * SL + j) * DM + d] = s;
  }
}

// ------- reduce partials + relu + residual + LayerNorm (per (b,j) row) ------
__global__ __launch_bounds__(256) void ln_k(float* __restrict__ Hs,
    const float* __restrict__ part, const float* __restrict__ g,
    const float* __restrict__ be, int last, u16* __restrict__ Hs_bf) {
  int j = blockIdx.x, b = blockIdx.y, d = threadIdx.x;
  size_t base = ((size_t)b * SL + j) * DM + d;
  float inf = 0.f;
#pragma unroll
  for (int icc = 0; icc < NCHUNK; ++icc)
    inf += part[(((size_t)icc * NB + b) * SL + j) * DM + d];
  float h = Hs[base] + fmaxf(inf, 0.f);
  float s1 = h, s2 = h * h;
#pragma unroll
  for (int m = 1; m < 64; m <<= 1) {
    s1 += __shfl_xor(s1, m);
    s2 += __shfl_xor(s2, m);
  }
  __shared__ float r1[4], r2[4];
  int wv = d >> 6;
  if ((d & 63) == 0) { r1[wv] = s1; r2[wv] = s2; }
  __syncthreads();
  s1 = r1[0] + r1[1] + r1[2] + r1[3];
  s2 = r2[0] + r2[1] + r2[2] + r2[3];
  float mu = s1 * (1.f / 256.f);
  float var = s2 * (1.f / 256.f) - mu * mu;
  float o = (h - mu) * rsqrtf(var + 1e-5f) * g[d] + be[d];
  Hs[base] = o;
  if (last) Hs_bf[base] = f2bf(o);
}

// ----------------- output expansion attention + Y (bf16) --------------------
__global__ __launch_bounds__(128) void attn_out_k(const float* __restrict__ Qo,
    const float* __restrict__ Kf, const float* __restrict__ Vf,
    u16* __restrict__ Ybf) {
  int bs = blockIdx.x, t = threadIdx.x;
  int b = bs >> 9;
  __shared__ float s_q[DM];
  __shared__ float s_p[SL];
  __shared__ float sred[2];
  s_q[t] = Qo[(size_t)bs * DM + t];
  s_q[t + 128] = Qo[(size_t)bs * DM + t + 128];
  __syncthreads();
  const float* kr = Kf + ((size_t)b * SL + t) * DM;
  float sc = 0.f;
#pragma unroll 8
  for (int d = 0; d < DM; ++d) sc += s_q[d] * kr[d];
  sc *= 0.0625f;
  float mx = sc;
#pragma unroll
  for (int m = 1; m < 64; m <<= 1) mx = fmaxf(mx, __shfl_xor(mx, m));
  if ((t & 63) == 0) sred[t >> 6] = mx;
  __syncthreads();
  mx = fmaxf(sred[0], sred[1]);
  float p = expf(sc - mx);
  float sum = p;
#pragma unroll
  for (int m = 1; m < 64; m <<= 1) sum += __shfl_xor(sum, m);
  __syncthreads();
  if ((t & 63) == 0) sred[t >> 6] = sum;
  __syncthreads();
  sum = sred[0] + sred[1];
  s_p[t] = p / sum;
  __syncthreads();
  for (int dd = t; dd < DM; dd += 128) {
    float y = 0.f;
    const float* vp = Vf + (size_t)b * SL * DM + dd;
#pragma unroll 8
    for (int k2 = 0; k2 < SL; ++k2) y += s_p[k2] * vp[(size_t)k2 * DM];
    Ybf[(size_t)bs * DM + dd] = f2bf(y);
  }
}

extern "C" void kernel_launch(void* const* d_in, const int* in_sizes, int n_in,
                              void* d_out, int out_size, void* d_ws,
                              size_t ws_size, hipStream_t stream) {
  (void)in_sizes; (void)n_in; (void)out_size;
  const int* ids = (const int*)d_in[0];
  const int* amask = (const int*)d_in[1];
  const float* tok = (const float*)d_in[2];
  const float* pos = (const float*)d_in[3];
  const float* Hsl = (const float*)d_in[4];
  const float* Ws = (const float*)d_in[5];
  const float* Wt = (const float*)d_in[6];
  const float* wq_in = (const float*)d_in[7];
  const float* wk_sl = (const float*)d_in[8];
  const float* wv_in = (const float*)d_in[9];
  const float* wq_out = (const float*)d_in[10];
  const float* wk_fin = (const float*)d_in[11];
  const float* wv_fin = (const float*)d_in[12];
  const float* w_out = (const float*)d_in[13];
  const float* lng = (const float*)d_in[14];
  const float* lnb = (const float*)d_in[15];

  char* base = (char*)d_ws;
  size_t used = 0;
  auto carve = [&](size_t bytes) {
    void* r = base + used;
    used += (bytes + 255) & ~(size_t)255;
    return r;
  };
  u16* x_bf = (u16*)carve((size_t)2048 * 256 * 2);
  float* Qi = (float*)carve((size_t)2048 * 256 * 4);
  float* Vi = (float*)carve((size_t)2048 * 256 * 4);
  float* Qo = (float*)carve((size_t)2048 * 256 * 4);
  float* Ksl = (float*)carve((size_t)128 * 256 * 4);
  float* Aat = (float*)carve((size_t)4 * 512 * 128 * 4);
  float* dpart = (float*)carve((size_t)16 * 512 * 4);
  float* Hst = (float*)carve((size_t)4 * 128 * 256 * 4);
  u16* Hs_bf = (u16*)carve((size_t)4 * 128 * 256 * 2);
  float* part = (float*)carve((size_t)NCHUNK * 4 * 128 * 256 * 4);
  float* Kf = (float*)carve((size_t)4 * 128 * 256 * 4);
  float* Vf = (float*)carve((size_t)4 * 128 * 256 * 4);
  u16* Ybf = (u16*)carve((size_t)2048 * 256 * 2);
  u16* wbase = (u16*)carve((size_t)6 * 65536 * 2);
  u16* Hbf = (u16*)carve((size_t)128 * 256 * 2);
  u16* w_out_bf = (u16*)carve((size_t)32000 * 256 * 2);
  const size_t WN = (size_t)128 * 128 * 256 * 32;
  bool bigws = (used + 2 * WN * 2 + 512) <= ws_size;
  u16* Ws_bf = nullptr;
  u16* Wt_bf = nullptr;
  if (bigws) {
    Ws_bf = (u16*)carve(WN * 2);
    Wt_bf = (u16*)carve(WN * 2);
  }

  CvtJobs cj;
  cj.src[0] = wq_in; cj.src[1] = wk_sl; cj.src[2] = wv_in;
  cj.src[3] = wq_out; cj.src[4] = wk_fin; cj.src[5] = wv_fin;
  cj.src[6] = Hsl;
  cvt_all_k<<<dim3(64, 7), 256, 0, stream>>>(cj, wbase, Hbf);
  cvt_k<<<2048, 256, 0, stream>>>(w_out, w_out_bf, (int)(32000 * 256 / 4));

  embed_k<<<2048, 256, 0, stream>>>(ids, tok, pos, x_bf);
  gemm_nt3<<<dim3(32, 4, 3), 256, 0, stream>>>(x_bf, wbase, Qi, 0, 2, 3,
                                               (size_t)2048 * 256);
  gemm_nt<<<dim3(2, 4), 256, 0, stream>>>(Hbf, wbase + (size_t)1 * 65536, Ksl,
                                          256);
  attn_in_k<<<2048, 128, 0, stream>>>(Qi, Ksl, amask, Aat);
  colsum_k<<<16, 512, 0, stream>>>(Aat, dpart);
  irhs_k<<<dim3(128, 4), 256, 0, stream>>>(Aat, Vi, dpart, Hsl, Hst);
  for (int step = 0; step < 6; ++step) {
    if (bigws) {
      if (step == 0)
        bilinear_k<1><<<dim3(SL, NCHUNK), 256, 0, stream>>>(Hst, Ws, Wt, Ws_bf,
                                                            Wt_bf, part);
      else
        bilinear_k<0><<<dim3(SL, NCHUNK), 256, 0, stream>>>(
            Hst, Ws_bf, Wt_bf, nullptr, nullptr, part);
    } else {
      bilinear_k<2><<<dim3(SL, NCHUNK), 256, 0, stream>>>(Hst, Ws, Wt, nullptr,
                                                          nullptr, part);
    }
    ln_k<<<dim3(128, 4), 256, 0, stream>>>(Hst, part, lng + step * DM,
                                           lnb + step * DM, step == 5 ? 1 : 0,
                                           Hs_bf);
  }
  gemm_nt3<<<dim3(8, 4, 2), 256, 0, stream>>>(Hs_bf, wbase, Kf, 4, 5, 5,
                                              (size_t)4 * 128 * 256);
  attn_out_k<<<2048, 128, 0, stream>>>(Qo, Kf, Vf, Ybf);
  gemm128<<<dim3(250, 16), 512, 0, stream>>>(Ybf, w_out_bf, (float*)d_out,
                                             32000);
}

// Round 10
// 1024.059 us; speedup vs baseline: 1.5651x; 1.0053x over previous
//
#include <hip/hip_runtime.h>

typedef unsigned short u16;
typedef unsigned int u32;
typedef unsigned long long u64;
typedef short short8_t __attribute__((ext_vector_type(8)));
typedef float f32x4 __attribute__((ext_vector_type(4)));

#define SL 128
#define DM 256
#define RK 32
#define SEQ 512
#define NB 4
#define NCHUNK 16

__device__ __forceinline__ float bf2f(u16 u) {
  return __uint_as_float(((unsigned int)u) << 16);
}
__device__ __forceinline__ u16 f2bf(float f) {
  unsigned int x = __float_as_uint(f);
  x += 0x7fffu + ((x >> 16) & 1u);
  return (u16)(x >> 16);
}

// ----------------- f32 -> bf16 conversion (vectorized) ----------------------
__global__ __launch_bounds__(256) void cvt_k(const float* __restrict__ in,
                                             u16* __restrict__ out, int n4) {
  for (int i = blockIdx.x * blockDim.x + threadIdx.x; i < n4;
       i += gridDim.x * blockDim.x) {
    float4 v = ((const float4*)in)[i];
    unsigned int lo = (unsigned)f2bf(v.x) | ((unsigned)f2bf(v.y) << 16);
    unsigned int hi = (unsigned)f2bf(v.z) | ((unsigned)f2bf(v.w) << 16);
    ((uint2*)out)[i] = make_uint2(lo, hi);
  }
}

// ------- batched small cvt: 6 square weights (64K elems) + H (32K) ---------
struct CvtJobs { const float* src[7]; };
__global__ __launch_bounds__(256) void cvt_all_k(CvtJobs jobs,
    u16* __restrict__ wbase, u16* __restrict__ Hbf) {
  int z = blockIdx.y;
  const float* in = jobs.src[z];
  u16* out = (z < 6) ? (wbase + (size_t)z * 65536) : Hbf;
  int n4 = (z < 6) ? 16384 : 8192;
  for (int i = blockIdx.x * 256 + threadIdx.x; i < n4; i += gridDim.x * 256) {
    float4 v = ((const float4*)in)[i];
    unsigned int lo = (unsigned)f2bf(v.x) | ((unsigned)f2bf(v.y) << 16);
    unsigned int hi = (unsigned)f2bf(v.z) | ((unsigned)f2bf(v.w) << 16);
    ((uint2*)out)[i] = make_uint2(lo, hi);
  }
}

// ---------------- embedding: x = tok[id] + pos[s] (bf16 out) ----------------
__global__ __launch_bounds__(256) void embed_k(const int* __restrict__ ids,
    const float* __restrict__ tok, const float* __restrict__ pos,
    u16* __restrict__ xbf) {
  int bs = blockIdx.x, d = threadIdx.x;
  int id = ids[bs];
  int s = bs & (SEQ - 1);
  float v = tok[(size_t)id * DM + d] + pos[(size_t)s * DM + d];
  xbf[(size_t)bs * DM + d] = f2bf(v);
}

// ------------- generic NT GEMM: C[M,N] = A[M,256] * B[N,256]^T --------------
__global__ __launch_bounds__(256) void gemm_nt(const u16* __restrict__ A,
    const u16* __restrict__ Bw, float* __restrict__ Cout, int N) {
  __shared__ u16 s_a[64 * 256];
  __shared__ u16 s_b[64 * 256];
  int tid = threadIdx.x;
  int m0 = blockIdx.x * 64, n0 = blockIdx.y * 64;
  for (int c = tid; c < 2048; c += 256) {
    int row = c >> 5;
    int ec = (c & 31) << 3;
    short8_t va = *(const short8_t*)(A + (size_t)(m0 + row) * 256 + ec);
    short8_t vb = *(const short8_t*)(Bw + (size_t)(n0 + row) * 256 + ec);
    int sw = ec ^ ((row & 7) << 3);
    *(short8_t*)(&s_a[row * 256 + sw]) = va;
    *(short8_t*)(&s_b[row * 256 + sw]) = vb;
  }
  __syncthreads();
  int lane = tid & 63;
  int w = tid >> 6;
  int wm = (w >> 1) * 32, wn = (w & 1) * 32;
  int lr = lane & 15, lk = (lane >> 4) << 3;
  f32x4 acc00 = {0.f, 0.f, 0.f, 0.f};
  f32x4 acc01 = {0.f, 0.f, 0.f, 0.f};
  f32x4 acc10 = {0.f, 0.f, 0.f, 0.f};
  f32x4 acc11 = {0.f, 0.f, 0.f, 0.f};
#pragma unroll
  for (int ks = 0; ks < 8; ++ks) {
    int ke = ks * 32 + lk;
    int r0 = wm + lr, r1 = wm + 16 + lr;
    int c0 = wn + lr, c1 = wn + 16 + lr;
    short8_t a0 = *(const short8_t*)(&s_a[r0 * 256 + (ke ^ ((r0 & 7) << 3))]);
    short8_t a1 = *(const short8_t*)(&s_a[r1 * 256 + (ke ^ ((r1 & 7) << 3))]);
    short8_t b0 = *(const short8_t*)(&s_b[c0 * 256 + (ke ^ ((c0 & 7) << 3))]);
    short8_t b1 = *(const short8_t*)(&s_b[c1 * 256 + (ke ^ ((c1 & 7) << 3))]);
    acc00 = __builtin_amdgcn_mfma_f32_16x16x32_bf16(a0, b0, acc00, 0, 0, 0);
    acc01 = __builtin_amdgcn_mfma_f32_16x16x32_bf16(a0, b1, acc01, 0, 0, 0);
    acc10 = __builtin_amdgcn_mfma_f32_16x16x32_bf16(a1, b0, acc10, 0, 0, 0);
    acc11 = __builtin_amdgcn_mfma_f32_16x16x32_bf16(a1, b1, acc11, 0, 0, 0);
  }
  int rbase = (lane >> 4) << 2;
#pragma unroll
  for (int i = 0; i < 2; ++i) {
#pragma unroll
    for (int jj = 0; jj < 2; ++jj) {
      f32x4 v = (i == 0) ? (jj == 0 ? acc00 : acc01)
                         : (jj == 0 ? acc10 : acc11);
      int row0 = m0 + wm + i * 16 + rbase;
      int col = n0 + wn + jj * 16 + lr;
#pragma unroll
      for (int q = 0; q < 4; ++q)
        Cout[(size_t)(row0 + q) * (size_t)N + col] = v[q];
    }
  }
}

// ---- z-batched NT GEMM (N=256): B = wbase + qsel(z)*64K, C = Cb + z*cs -----
__global__ __launch_bounds__(256) void gemm_nt3(const u16* __restrict__ A,
    const u16* __restrict__ wbase, float* __restrict__ Cbase, int q0, int q1,
    int q2, size_t cstride) {
  int z = blockIdx.z;
  int q = (z == 0) ? q0 : ((z == 1) ? q1 : q2);
  const u16* Bw = wbase + (size_t)q * 65536;
  float* Cout = Cbase + (size_t)z * cstride;
  __shared__ u16 s_a[64 * 256];
  __shared__ u16 s_b[64 * 256];
  int tid = threadIdx.x;
  int m0 = blockIdx.x * 64, n0 = blockIdx.y * 64;
  for (int c = tid; c < 2048; c += 256) {
    int row = c >> 5;
    int ec = (c & 31) << 3;
    short8_t va = *(const short8_t*)(A + (size_t)(m0 + row) * 256 + ec);
    short8_t vb = *(const short8_t*)(Bw + (size_t)(n0 + row) * 256 + ec);
    int sw = ec ^ ((row & 7) << 3);
    *(short8_t*)(&s_a[row * 256 + sw]) = va;
    *(short8_t*)(&s_b[row * 256 + sw]) = vb;
  }
  __syncthreads();
  int lane = tid & 63;
  int w = tid >> 6;
  int wm = (w >> 1) * 32, wn = (w & 1) * 32;
  int lr = lane & 15, lk = (lane >> 4) << 3;
  f32x4 acc00 = {0.f, 0.f, 0.f, 0.f};
  f32x4 acc01 = {0.f, 0.f, 0.f, 0.f};
  f32x4 acc10 = {0.f, 0.f, 0.f, 0.f};
  f32x4 acc11 = {0.f, 0.f, 0.f, 0.f};
#pragma unroll
  for (int ks = 0; ks < 8; ++ks) {
    int ke = ks * 32 + lk;
    int r0 = wm + lr, r1 = wm + 16 + lr;
    int c0 = wn + lr, c1 = wn + 16 + lr;
    short8_t a0 = *(const short8_t*)(&s_a[r0 * 256 + (ke ^ ((r0 & 7) << 3))]);
    short8_t a1 = *(const short8_t*)(&s_a[r1 * 256 + (ke ^ ((r1 & 7) << 3))]);
    short8_t b0 = *(const short8_t*)(&s_b[c0 * 256 + (ke ^ ((c0 & 7) << 3))]);
    short8_t b1 = *(const short8_t*)(&s_b[c1 * 256 + (ke ^ ((c1 & 7) << 3))]);
    acc00 = __builtin_amdgcn_mfma_f32_16x16x32_bf16(a0, b0, acc00, 0, 0, 0);
    acc01 = __builtin_amdgcn_mfma_f32_16x16x32_bf16(a0, b1, acc01, 0, 0, 0);
    acc10 = __builtin_amdgcn_mfma_f32_16x16x32_bf16(a1, b0, acc10, 0, 0, 0);
    acc11 = __builtin_amdgcn_mfma_f32_16x16x32_bf16(a1, b1, acc11, 0, 0, 0);
  }
  int rbase = (lane >> 4) << 2;
#pragma unroll
  for (int i = 0; i < 2; ++i) {
#pragma unroll
    for (int jj = 0; jj < 2; ++jj) {
      f32x4 v = (i == 0) ? (jj == 0 ? acc00 : acc01)
                         : (jj == 0 ? acc10 : acc11);
      int row0 = m0 + wm + i * 16 + rbase;
      int col = n0 + wn + jj * 16 + lr;
#pragma unroll
      for (int q = 0; q < 4; ++q)
        Cout[(size_t)(row0 + q) * 256 + col] = v[q];
    }
  }
}

// ------ logits GEMM: 128x128 tile, K=256 in two 64KB LDS stages, NT C ------
__global__ __launch_bounds__(512) void gemm128(const u16* __restrict__ A,
    const u16* __restrict__ Bw, float* __restrict__ Cout, int N) {
  __shared__ u16 s_a[128 * 128];
  __shared__ u16 s_b[128 * 128];
  int tid = threadIdx.x;
  int n0 = blockIdx.x * 128, m0 = blockIdx.y * 128;
  int lane = tid & 63, w = tid >> 6;
  int wm = (w >> 1) * 32;
  int wn = (w & 1) * 64;
  int lr = lane & 15, lk = (lane >> 4) << 3;
  f32x4 acc[2][4];
#pragma unroll
  for (int i = 0; i < 2; ++i)
#pragma unroll
    for (int t = 0; t < 4; ++t) acc[i][t] = {0.f, 0.f, 0.f, 0.f};
#pragma unroll
  for (int kc = 0; kc < 2; ++kc) {
    if (kc) __syncthreads();
    for (int c = tid; c < 2048; c += 512) {
      int row = c >> 4;
      int ec = (c & 15) << 3;
      short8_t va =
          *(const short8_t*)(A + (size_t)(m0 + row) * 256 + kc * 128 + ec);
      short8_t vb =
          *(const short8_t*)(Bw + (size_t)(n0 + row) * 256 + kc * 128 + ec);
      int sw = ec ^ ((row & 7) << 3);
      *(short8_t*)(&s_a[row * 128 + sw]) = va;
      *(short8_t*)(&s_b[row * 128 + sw]) = vb;
    }
    __syncthreads();
#pragma unroll
    for (int ks = 0; ks < 4; ++ks) {
      int ke = ks * 32 + lk;
      int r0 = wm + lr, r1 = wm + 16 + lr;
      short8_t a0 =
          *(const short8_t*)(&s_a[r0 * 128 + (ke ^ ((r0 & 7) << 3))]);
      short8_t a1 =
          *(const short8_t*)(&s_a[r1 * 128 + (ke ^ ((r1 & 7) << 3))]);
#pragma unroll
      for (int t = 0; t < 4; ++t) {
        int c0 = wn + t * 16 + lr;
        short8_t b0 =
            *(const short8_t*)(&s_b[c0 * 128 + (ke ^ ((c0 & 7) << 3))]);
        acc[0][t] = __builtin_amdgcn_mfma_f32_16x16x32_bf16(a0, b0, acc[0][t], 0, 0, 0);
        acc[1][t] = __builtin_amdgcn_mfma_f32_16x16x32_bf16(a1, b0, acc[1][t], 0, 0, 0);
      }
    }
  }
  int rbase = (lane >> 4) << 2;
#pragma unroll
  for (int i = 0; i < 2; ++i) {
#pragma unroll
    for (int t = 0; t < 4; ++t) {
      int row0 = m0 + wm + i * 16 + rbase;
      int col = n0 + wn + t * 16 + lr;
#pragma unroll
      for (int q = 0; q < 4; ++q)
        __builtin_nontemporal_store(acc[i][t][q],
                                    &Cout[(size_t)(row0 + q) * (size_t)N + col]);
    }
  }
}

// ------- input compression attention: softmax over slots, then mask ---------
__global__ __launch_bounds__(128) void attn_in_k(const float* __restrict__ Qi,
    const float* __restrict__ Ksl, const int* __restrict__ am,
    float* __restrict__ Aout) {
  int bs = blockIdx.x, t = threadIdx.x;
  __shared__ float s_q[DM];
  __shared__ float sred[2];
  s_q[t] = Qi[(size_t)bs * DM + t];
  s_q[t + 128] = Qi[(size_t)bs * DM + t + 128];
  __syncthreads();
  const float* kr = Ksl + (size_t)t * DM;
  float sc = 0.f;
#pragma unroll 8
  for (int d = 0; d < DM; ++d) sc += s_q[d] * kr[d];
  sc *= 0.0625f;
  float mx = sc;
#pragma unroll
  for (int m = 1; m < 64; m <<= 1) mx = fmaxf(mx, __shfl_xor(mx, m));
  if ((t & 63) == 0) sred[t >> 6] = mx;
  __syncthreads();
  mx = fmaxf(sred[0], sred[1]);
  float p = expf(sc - mx);
  float sum = p;
#pragma unroll
  for (int m = 1; m < 64; m <<= 1) sum += __shfl_xor(sum, m);
  __syncthreads();
  if ((t & 63) == 0) sred[t >> 6] = sum;
  __syncthreads();
  sum = sred[0] + sred[1];
  p = (p / sum) * (float)am[bs];
  Aout[(size_t)bs * SL + t] = p;
}

// ---- partial column sums: dpart[sl][b*SL+k] = sum of 32 si; 16 slices ------
__global__ __launch_bounds__(512) void colsum_k(const float* __restrict__ A,
                                                float* __restrict__ dpart) {
  int t = threadIdx.x;
  int b = t >> 7, k = t & (SL - 1);
  int s0 = blockIdx.x * 32;
  const float* ap = A + (size_t)b * SEQ * SL + (size_t)s0 * SL + k;
  float s = 0.f;
#pragma unroll 4
  for (int si = 0; si < 32; ++si) s += ap[(size_t)si * SL];
  dpart[blockIdx.x * 512 + t] = s;
}

// ------ IR[b,k,d] = sum_s A[b,s,k]*Vi[b,s,d] / den;  Hs = H + IR ------------
__global__ __launch_bounds__(256) void irhs_k(const float* __restrict__ A,
    const float* __restrict__ Vi, const float* __restrict__ dpart,
    const float* __restrict__ H, float* __restrict__ Hs) {
  int k = blockIdx.x, b = blockIdx.y, d = threadIdx.x;
  float den = 1e-8f;
#pragma unroll
  for (int i = 0; i < 16; ++i) den += dpart[i * 512 + b * SL + k];
  const float* ap = A + (size_t)b * SEQ * SL + k;
  const float* vp = Vi + (size_t)b * SEQ * DM + d;
  float s = 0.f;
#pragma unroll 4
  for (int si = 0; si < SEQ; ++si)
    s += ap[(size_t)si * SL] * vp[(size_t)si * DM];
  Hs[((size_t)b * SL + k) * DM + d] = H[(size_t)k * DM + d] + s / den;
}

// -------------------- bilinear all-pairs slot mixing ------------------------
// ONE pair (i,j) per wave (R6-proven no-spill body); 512-thread blocks =
// 8 waves; block (j, ic) covers i in [ic*8, ic*8+8). NCHUNK=16 partials.
// Hs read directly from L2 (no LDS staging) -> LDS 37 KB -> ~3 blocks/CU
// (~24 waves/CU) for TLP latency hiding.
// MODE 0: bf16 W. MODE 1: f32 W chunked 8-bursts + NT-write bf16 slabs.
// MODE 2: f32, no write.
template <int MODE>
__global__ __launch_bounds__(512) void bilinear_k(
    const float* __restrict__ Hs, const void* __restrict__ Wsv,
    const void* __restrict__ Wtv, u16* __restrict__ Wsb,
    u16* __restrict__ Wtb, float* __restrict__ part) {
  int j = blockIdx.x, ic = blockIdx.y, tid = threadIdx.x;
  int wv = tid >> 6, ln = tid & 63;
  __shared__ float s_int[8][NB][RK];  // 4 KB, per-wave slot
  __shared__ float s_acc[8][NB][DM];  // 32 KB, per-wave slot
  int i = ic * 8 + wv;

  if constexpr (MODE == 0) {
    const u16* Wsp = (const u16*)Wsv;
    const u16* Wtp = (const u16*)Wtv;
    float iacc[NB][8];
#pragma unroll
    for (int b = 0; b < NB; ++b)
#pragma unroll
      for (int q = 0; q < 8; ++q) iacc[b][q] = 0.f;
    if (i != j) {
      size_t slab = (size_t)(i * SL + j) * (DM * RK);
      const u16* wp = Wsp + slab;
      const u16* tp = Wtp + slab;
      short8_t wsr[16], wtr[16];
#pragma unroll
      for (int t = 0; t < 16; ++t)
        wsr[t] = __builtin_nontemporal_load(
            (const short8_t*)(wp + t * 512 + ln * 8));
#pragma unroll
      for (int t = 0; t < 16; ++t)
        wtr[t] = __builtin_nontemporal_load(
            (const short8_t*)(tp + t * 512 + ln * 8));
      float racc[NB][8];
#pragma unroll
      for (int b = 0; b < NB; ++b)
#pragma unroll
        for (int q = 0; q < 8; ++q) racc[b][q] = 0.f;
#pragma unroll
      for (int t = 0; t < 16; ++t) {
        int d = t * 16 + (ln >> 2);
        float h0 = Hs[((size_t)0 * SL + i) * DM + d];
        float h1 = Hs[((size_t)1 * SL + i) * DM + d];
        float h2 = Hs[((size_t)2 * SL + i) * DM + d];
        float h3 = Hs[((size_t)3 * SL + i) * DM + d];
#pragma unroll
        for (int q = 0; q < 8; ++q) {
          float wf = bf2f((u16)wsr[t][q]);
          racc[0][q] += h0 * wf;
          racc[1][q] += h1 * wf;
          racc[2][q] += h2 * wf;
          racc[3][q] += h3 * wf;
        }
      }
#pragma unroll
      for (int m = 4; m <= 32; m <<= 1)
#pragma unroll
        for (int b = 0; b < NB; ++b)
#pragma unroll
          for (int q = 0; q < 8; ++q) racc[b][q] += __shfl_xor(racc[b][q], m);
      if ((ln >> 2) == 0) {
        int r0 = (ln & 3) * 8;
#pragma unroll
        for (int b = 0; b < NB; ++b)
#pragma unroll
          for (int q = 0; q < 8; ++q) s_int[wv][b][r0 + q] = racc[b][q];
      }
      // same-wave LDS write->read: in-order, no barrier needed
#pragma unroll
      for (int t = 0; t < 16; ++t) {
        int r = t * 2 + (ln >> 5);
        float v0 = s_int[wv][0][r], v1 = s_int[wv][1][r];
        float v2 = s_int[wv][2][r], v3 = s_int[wv][3][r];
#pragma unroll
        for (int q = 0; q < 8; ++q) {
          float wf = bf2f((u16)wtr[t][q]);
          iacc[0][q] += v0 * wf;
          iacc[1][q] += v1 * wf;
          iacc[2][q] += v2 * wf;
          iacc[3][q] += v3 * wf;
        }
      }
    }
#pragma unroll
    for (int b = 0; b < NB; ++b)
#pragma unroll
      for (int q = 0; q < 8; ++q) iacc[b][q] += __shfl_xor(iacc[b][q], 32);
    if (ln < 32) {
#pragma unroll
      for (int b = 0; b < NB; ++b)
#pragma unroll
        for (int q = 0; q < 8; ++q) s_acc[wv][b][ln * 8 + q] = iacc[b][q];
    }
  } else {
    const float* Wsp = (const float*)Wsv;
    const float* Wtp = (const float*)Wtv;
    size_t slab = (size_t)(i * SL + j) * (DM * RK);
    const float* wp = Wsp + slab;
    const float* tp = Wtp + slab;
    float iacc[NB][4];
#pragma unroll
    for (int b = 0; b < NB; ++b)
#pragma unroll
      for (int q = 0; q < 4; ++q) iacc[b][q] = 0.f;
    float racc[NB][4];
#pragma unroll
    for (int b = 0; b < NB; ++b)
#pragma unroll
      for (int q = 0; q < 4; ++q) racc[b][q] = 0.f;
    // S-phase in 4 chunks of 8 f32x4 (keeps ~32 data regs live)
#pragma unroll
    for (int c8 = 0; c8 < 4; ++c8) {
      f32x4 wsr[8];
#pragma unroll
      for (int t = 0; t < 8; ++t)
        wsr[t] = __builtin_nontemporal_load(
            (const f32x4*)(wp + (c8 * 8 + t) * 256 + ln * 4));
#pragma unroll
      for (int t = 0; t < 8; ++t) {
        int tt = c8 * 8 + t;
        f32x4 w4 = wsr[t];
        int d = tt * 8 + (ln >> 3);
#pragma unroll
        for (int b = 0; b < NB; ++b) {
          float h = Hs[((size_t)b * SL + i) * DM + d];
          racc[b][0] += h * w4[0];
          racc[b][1] += h * w4[1];
          racc[b][2] += h * w4[2];
          racc[b][3] += h * w4[3];
        }
        if constexpr (MODE == 1) {
          u64 pk =
              (u64)((unsigned)f2bf(w4[0]) | ((unsigned)f2bf(w4[1]) << 16)) |
              ((u64)((unsigned)f2bf(w4[2]) | ((unsigned)f2bf(w4[3]) << 16))
               << 32);
          __builtin_nontemporal_store(pk,
                                      (u64*)(Wsb + slab + tt * 256 + ln * 4));
        }
      }
    }
    if (i != j) {
#pragma unroll
      for (int m = 8; m <= 32; m <<= 1)
#pragma unroll
        for (int b = 0; b < NB; ++b)
#pragma unroll
          for (int q = 0; q < 4; ++q) racc[b][q] += __shfl_xor(racc[b][q], m);
      if ((ln >> 3) == 0) {
        int r0 = (ln & 7) * 4;
#pragma unroll
        for (int b = 0; b < NB; ++b)
#pragma unroll
          for (int q = 0; q < 4; ++q) s_int[wv][b][r0 + q] = racc[b][q];
      }
    }
#pragma unroll
    for (int c8 = 0; c8 < 4; ++c8) {
      f32x4 wtr[8];
#pragma unroll
      for (int t = 0; t < 8; ++t)
        wtr[t] = __builtin_nontemporal_load(
            (const f32x4*)(tp + (c8 * 8 + t) * 256 + ln * 4));
#pragma unroll
      for (int t = 0; t < 8; ++t) {
        int r = c8 * 8 + t;
        f32x4 w4 = wtr[t];
        if constexpr (MODE == 1) {
          u64 pk =
              (u64)((unsigned)f2bf(w4[0]) | ((unsigned)f2bf(w4[1]) << 16)) |
              ((u64)((unsigned)f2bf(w4[2]) | ((unsigned)f2bf(w4[3]) << 16))
               << 32);
          __builtin_nontemporal_store(pk,
                                      (u64*)(Wtb + slab + r * 256 + ln * 4));
        }
        if (i != j) {
          float v0 = s_int[wv][0][r], v1 = s_int[wv][1][r];
          float v2 = s_int[wv][2][r], v3 = s_int[wv][3][r];
          iacc[0][0] += v0 * w4[0]; iacc[0][1] += v0 * w4[1];
          iacc[0][2] += v0 * w4[2]; iacc[0][3] += v0 * w4[3];
          iacc[1][0] += v1 * w4[0]; iacc[1][1] += v1 * w4[1];
          iacc[1][2] += v1 * w4[2]; iacc[1][3] += v1 * w4[3];
          iacc[2][0] += v2 * w4[0]; iacc[2][1] += v2 * w4[1];
          iacc[2][2] += v2 * w4[2]; iacc[2][3] += v2 * w4[3];
          iacc[3][0] += v3 * w4[0]; iacc[3][1] += v3 * w4[1];
          iacc[3][2] += v3 * w4[2]; iacc[3][3] += v3 * w4[3];
        }
      }
    }
#pragma unroll
    for (int b = 0; b < NB; ++b)
#pragma unroll
      for (int q = 0; q < 4; ++q) s_acc[wv][b][ln * 4 + q] = iacc[b][q];
  }
  __syncthreads();
  for (int c = tid; c < NB * DM; c += 512) {
    int b = c >> 8, d = c & 255;
    float s = 0.f;
#pragma unroll
    for (int w8 = 0; w8 < 8; ++w8) s += s_acc[w8][b][d];
    part[(((size_t)ic * NB + b) * SL + j) * DM + d] = s;
  }
}

// ------- reduce partials + relu + residual + LayerNorm (per (b,j) row) ------
__global__ __launch_bounds__(256) void ln_k(float* __restrict__ Hs,
    const float* __restrict__ part, const float* __restrict__ g,
    const float* __restrict__ be, int last, u16* __restrict__ Hs_bf) {
  int j = blockIdx.x, b = blockIdx.y, d = threadIdx.x;
  size_t base = ((size_t)b * SL + j) * DM + d;
  float inf = 0.f;
#pragma unroll
  for (int icc = 0; icc < NCHUNK; ++icc)
    inf += part[(((size_t)icc * NB + b) * SL + j) * DM + d];
  float h = Hs[base] + fmaxf(inf, 0.f);
  float s1 = h, s2 = h * h;
#pragma unroll
  for (int m = 1; m < 64; m <<= 1) {
    s1 += __shfl_xor(s1, m);
    s2 += __shfl_xor(s2, m);
  }
  __shared__ float r1[4], r2[4];
  int wv = d >> 6;
  if ((d & 63) == 0) { r1[wv] = s1; r2[wv] = s2; }
  __syncthreads();
  s1 = r1[0] + r1[1] + r1[2] + r1[3];
  s2 = r2[0] + r2[1] + r2[2] + r2[3];
  float mu = s1 * (1.f / 256.f);
  float var = s2 * (1.f / 256.f) - mu * mu;
  float o = (h - mu) * rsqrtf(var + 1e-5f) * g[d] + be[d];
  Hs[base] = o;
  if (last) Hs_bf[base] = f2bf(o);
}

// ----------------- output expansion attention + Y (bf16) --------------------
__global__ __launch_bounds__(128) void attn_out_k(const float* __restrict__ Qo,
    const float* __restrict__ Kf, const float* __restrict__ Vf,
    u16* __restrict__ Ybf) {
  int bs = blockIdx.x, t = threadIdx.x;
  int b = bs >> 9;
  __shared__ float s_q[DM];
  __shared__ float s_p[SL];
  __shared__ float sred[2];
  s_q[t] = Qo[(size_t)bs * DM + t];
  s_q[t + 128] = Qo[(size_t)bs * DM + t + 128];
  __syncthreads();
  const float* kr = Kf + ((size_t)b * SL + t) * DM;
  float sc = 0.f;
#pragma unroll 8
  for (int d = 0; d < DM; ++d) sc += s_q[d] * kr[d];
  sc *= 0.0625f;
  float mx = sc;
#pragma unroll
  for (int m = 1; m < 64; m <<= 1) mx = fmaxf(mx, __shfl_xor(mx, m));
  if ((t & 63) == 0) sred[t >> 6] = mx;
  __syncthreads();
  mx = fmaxf(sred[0], sred[1]);
  float p = expf(sc - mx);
  float sum = p;
#pragma unroll
  for (int m = 1; m < 64; m <<= 1) sum += __shfl_xor(sum, m);
  __syncthreads();
  if ((t & 63) == 0) sred[t >> 6] = sum;
  __syncthreads();
  sum = sred[0] + sred[1];
  s_p[t] = p / sum;
  __syncthreads();
  for (int dd = t; dd < DM; dd += 128) {
    float y = 0.f;
    const float* vp = Vf + (size_t)b * SL * DM + dd;
#pragma unroll 8
    for (int k2 = 0; k2 < SL; ++k2) y += s_p[k2] * vp[(size_t)k2 * DM];
    Ybf[(size_t)bs * DM + dd] = f2bf(y);
  }
}

extern "C" void kernel_launch(void* const* d_in, const int* in_sizes, int n_in,
                              void* d_out, int out_size, void* d_ws,
                              size_t ws_size, hipStream_t stream) {
  (void)in_sizes; (void)n_in; (void)out_size;
  const int* ids = (const int*)d_in[0];
  const int* amask = (const int*)d_in[1];
  const float* tok = (const float*)d_in[2];
  const float* pos = (const float*)d_in[3];
  const float* Hsl = (const float*)d_in[4];
  const float* Ws = (const float*)d_in[5];
  const float* Wt = (const float*)d_in[6];
  const float* wq_in = (const float*)d_in[7];
  const float* wk_sl = (const float*)d_in[8];
  const float* wv_in = (const float*)d_in[9];
  const float* wq_out = (const float*)d_in[10];
  const float* wk_fin = (const float*)d_in[11];
  const float* wv_fin = (const float*)d_in[12];
  const float* w_out = (const float*)d_in[13];
  const float* lng = (const float*)d_in[14];
  const float* lnb = (const float*)d_in[15];

  char* base = (char*)d_ws;
  size_t used = 0;
  auto carve = [&](size_t bytes) {
    void* r = base + used;
    used += (bytes + 255) & ~(size_t)255;
    return r;
  };
  u16* x_bf = (u16*)carve((size_t)2048 * 256 * 2);
  float* Qi = (float*)carve((size_t)2048 * 256 * 4);
  float* Vi = (float*)carve((size_t)2048 * 256 * 4);
  float* Qo = (float*)carve((size_t)2048 * 256 * 4);
  float* Ksl = (float*)carve((size_t)128 * 256 * 4);
  float* Aat = (float*)carve((size_t)4 * 512 * 128 * 4);
  float* dpart = (float*)carve((size_t)16 * 512 * 4);
  float* Hst = (float*)carve((size_t)4 * 128 * 256 * 4);
  u16* Hs_bf = (u16*)carve((size_t)4 * 128 * 256 * 2);
  float* part = (float*)carve((size_t)NCHUNK * 4 * 128 * 256 * 4);
  float* Kf = (float*)carve((size_t)4 * 128 * 256 * 4);
  float* Vf = (float*)carve((size_t)4 * 128 * 256 * 4);
  u16* Ybf = (u16*)carve((size_t)2048 * 256 * 2);
  u16* wbase = (u16*)carve((size_t)6 * 65536 * 2);
  u16* Hbf = (u16*)carve((size_t)128 * 256 * 2);
  u16* w_out_bf = (u16*)carve((size_t)32000 * 256 * 2);
  const size_t WN = (size_t)128 * 128 * 256 * 32;
  bool bigws = (used + 2 * WN * 2 + 512) <= ws_size;
  u16* Ws_bf = nullptr;
  u16* Wt_bf = nullptr;
  if (bigws) {
    Ws_bf = (u16*)carve(WN * 2);
    Wt_bf = (u16*)carve(WN * 2);
  }

  CvtJobs cj;
  cj.src[0] = wq_in; cj.src[1] = wk_sl; cj.src[2] = wv_in;
  cj.src[3] = wq_out; cj.src[4] = wk_fin; cj.src[5] = wv_fin;
  cj.src[6] = Hsl;
  cvt_all_k<<<dim3(64, 7), 256, 0, stream>>>(cj, wbase, Hbf);
  cvt_k<<<2048, 256, 0, stream>>>(w_out, w_out_bf, (int)(32000 * 256 / 4));

  embed_k<<<2048, 256, 0, stream>>>(ids, tok, pos, x_bf);
  gemm_nt3<<<dim3(32, 4, 3), 256, 0, stream>>>(x_bf, wbase, Qi, 0, 2, 3,
                                               (size_t)2048 * 256);
  gemm_nt<<<dim3(2, 4), 256, 0, stream>>>(Hbf, wbase + (size_t)1 * 65536, Ksl,
                                          256);
  attn_in_k<<<2048, 128, 0, stream>>>(Qi, Ksl, amask, Aat);
  colsum_k<<<16, 512, 0, stream>>>(Aat, dpart);
  irhs_k<<<dim3(128, 4), 256, 0, stream>>>(Aat, Vi, dpart, Hsl, Hst);
  for (int step = 0; step < 6; ++step) {
    if (bigws) {
      if (step == 0)
        bilinear_k<1><<<dim3(SL, NCHUNK), 512, 0, stream>>>(Hst, Ws, Wt, Ws_bf,
                                                            Wt_bf, part);
      else
        bilinear_k<0><<<dim3(SL, NCHUNK), 512, 0, stream>>>(
            Hst, Ws_bf, Wt_bf, nullptr, nullptr, part);
    } else {
      bilinear_k<2><<<dim3(SL, NCHUNK), 512, 0, stream>>>(Hst, Ws, Wt, nullptr,
                                                          nullptr, part);
    }
    ln_k<<<dim3(128, 4), 256, 0, stream>>>(Hst, part, lng + step * DM,
                                           lnb + step * DM, step == 5 ? 1 : 0,
                                           Hs_bf);
  }
  gemm_nt3<<<dim3(8, 4, 2), 256, 0, stream>>>(Hs_bf, wbase, Kf, 4, 5, 5,
                                              (size_t)4 * 128 * 256);
  attn_out_k<<<2048, 128, 0, stream>>>(Qo, Kf, Vf, Ybf);
  gemm128<<<dim3(250, 16), 512, 0, stream>>>(Ybf, w_out_bf, (float*)d_out,
                                             32000);
}